// Round 2
// baseline (2421.402 us; speedup 1.0000x reference)
//
#include <hip/hip_runtime.h>
#include <math.h>

// Problem constants
#define HW    65536      // H*W = 256*256
#define NPIX  262144     // B*H*W
#define EPSLN 1e-5f

// ---------------------------------------------------------------------------
// Kernel 1: LayerNorm(ch) + QKV projection (64 -> 192), one thread per pixel.
// Weights are wave-uniform -> scalar s_load batches; inner loop = v_fmac_f32.
// ---------------------------------------------------------------------------
__global__ __launch_bounds__(256) void k_ln_qkv(
    const float* __restrict__ x,  const float* __restrict__ g1,
    const float* __restrict__ b1, const float* __restrict__ wq,
    const float* __restrict__ bq, float* __restrict__ qkv)
{
    int p = blockIdx.x * 256 + threadIdx.x;
    if (p >= NPIX) return;
    int b  = p >> 16;
    int hw = p & 65535;

    const float* xp = x + ((size_t)b * 64) * HW + hw;
    float xv[64];
    float mu = 0.f;
#pragma unroll
    for (int c = 0; c < 64; ++c) { xv[c] = xp[(size_t)c * HW]; mu += xv[c]; }
    mu *= 0.015625f;
    float var = 0.f;
#pragma unroll
    for (int c = 0; c < 64; ++c) { float d = xv[c] - mu; var += d * d; }
    var *= 0.015625f;
    float inv = rsqrtf(var + EPSLN);
#pragma unroll
    for (int c = 0; c < 64; ++c) xv[c] = (xv[c] - mu) * inv * g1[c] + b1[c];

    float* qp = qkv + ((size_t)b * 192) * HW + hw;
    // 192 outputs; bound unroll to keep the body in I$ (inner 64 FMAs unroll).
#pragma unroll 2
    for (int o = 0; o < 192; ++o) {
        const float* wr = wq + o * 64;
        float a0 = bq[o], a1 = 0.f, a2 = 0.f, a3 = 0.f;
#pragma unroll
        for (int c = 0; c < 64; c += 4) {
            a0 += wr[c + 0] * xv[c + 0];
            a1 += wr[c + 1] * xv[c + 1];
            a2 += wr[c + 2] * xv[c + 2];
            a3 += wr[c + 3] * xv[c + 3];
        }
        qp[(size_t)o * HW] = (a0 + a1) + (a2 + a3);
    }
}

// ---------------------------------------------------------------------------
// Kernel 2: dilated 3x3 neighborhood attention (4 heads x 16 dim) + out-proj
// + residual. One thread per pixel. OOB neighbors: score = 0 (zero-pad
// semantics -> still in softmax), v = 0. Writes x1 = x + proj(attn) to d_out.
// ---------------------------------------------------------------------------
__global__ __launch_bounds__(256) void k_attn(
    const float* __restrict__ x,   const float* __restrict__ qkv,
    const float* __restrict__ wo,  const float* __restrict__ bo,
    float* __restrict__ x1)
{
    int p = blockIdx.x * 256 + threadIdx.x;
    if (p >= NPIX) return;
    int b  = p >> 16;
    int hw = p & 65535;
    int hh = hw >> 8;
    int ww = hw & 255;

    const float* base = qkv + ((size_t)b * 192) * HW;

    float out[64];
#pragma unroll
    for (int i = 0; i < 64; ++i) out[i] = 0.f;

#pragma unroll 1
    for (int head = 0; head < 4; ++head) {
        float q[16];
#pragma unroll
        for (int d = 0; d < 16; ++d)
            q[d] = base[(size_t)(head * 16 + d) * HW + hw] * 0.25f; // HD^-0.5

        float sc[9];
#pragma unroll
        for (int n = 0; n < 9; ++n) {
            int dy = (n / 3) * 2 - 2;
            int dx = (n % 3) * 2 - 2;
            int y = hh + dy, xw = ww + dx;
            float s = 0.f;
            if (y >= 0 && y < 256 && xw >= 0 && xw < 256) {
                int nhw = y * 256 + xw;
                const float* kp = base + (size_t)(64 + head * 16) * HW + nhw;
#pragma unroll
                for (int d = 0; d < 16; ++d) s += q[d] * kp[(size_t)d * HW];
            }
            sc[n] = s;
        }
        float mx = sc[0];
#pragma unroll
        for (int n = 1; n < 9; ++n) mx = fmaxf(mx, sc[n]);
        float sum = 0.f;
#pragma unroll
        for (int n = 0; n < 9; ++n) { sc[n] = __expf(sc[n] - mx); sum += sc[n]; }
        float isum = 1.f / sum;
#pragma unroll
        for (int n = 0; n < 9; ++n) {
            int dy = (n / 3) * 2 - 2;
            int dx = (n % 3) * 2 - 2;
            int y = hh + dy, xw = ww + dx;
            if (y >= 0 && y < 256 && xw >= 0 && xw < 256) {
                float a = sc[n] * isum;
                int nhw = y * 256 + xw;
                const float* vp = base + (size_t)(128 + head * 16) * HW + nhw;
#pragma unroll
                for (int d = 0; d < 16; ++d)
                    out[head * 16 + d] += a * vp[(size_t)d * HW];
            }
        }
    }

    // out-proj (64->64) + residual
    const float* xr = x + ((size_t)b * 64) * HW + hw;
    float*      x1p = x1 + ((size_t)b * 64) * HW + hw;
#pragma unroll 2
    for (int o = 0; o < 64; ++o) {
        const float* wr = wo + o * 64;
        float a0 = bo[o], a1 = 0.f, a2 = 0.f, a3 = 0.f;
#pragma unroll
        for (int c = 0; c < 64; c += 4) {
            a0 += wr[c + 0] * out[c + 0];
            a1 += wr[c + 1] * out[c + 1];
            a2 += wr[c + 2] * out[c + 2];
            a3 += wr[c + 3] * out[c + 3];
        }
        x1p[(size_t)o * HW] = xr[(size_t)o * HW] + ((a0 + a1) + (a2 + a3));
    }
}

// ---------------------------------------------------------------------------
// Kernel 3 (fused MLP): LN2 + FC1(64->256) + GELU + FC2(256->64) + GELU
// + residual, entirely per-pixel in registers. h never touches memory.
// h computed in 16-channel chunks (hv[16]) and immediately consumed.
// ---------------------------------------------------------------------------
__device__ __forceinline__ float gelu_exact(float v)
{
    return 0.5f * v * (1.f + erff(v * 0.70710678118654752f));
}

__global__ __launch_bounds__(256) void k_mlp(
    const float* __restrict__ g2, const float* __restrict__ b2,
    const float* __restrict__ w1, const float* __restrict__ bb1,
    const float* __restrict__ w2, const float* __restrict__ bb2,
    float* __restrict__ io)   // io = x1 (in), overwritten with final out
{
    int p = blockIdx.x * 256 + threadIdx.x;
    if (p >= NPIX) return;
    int b  = p >> 16;
    int hw = p & 65535;

    float* iop = io + ((size_t)b * 64) * HW + hw;

    float xv[64];
    float mu = 0.f;
#pragma unroll
    for (int c = 0; c < 64; ++c) { xv[c] = iop[(size_t)c * HW]; mu += xv[c]; }
    mu *= 0.015625f;
    float var = 0.f;
#pragma unroll
    for (int c = 0; c < 64; ++c) { float d = xv[c] - mu; var += d * d; }
    var *= 0.015625f;
    float inv = rsqrtf(var + EPSLN);
#pragma unroll
    for (int c = 0; c < 64; ++c) xv[c] = (xv[c] - mu) * inv * g2[c] + b2[c];

    float acc[64];
#pragma unroll
    for (int o = 0; o < 64; ++o) acc[o] = bb2[o];

    // FC1 + GELU in 16-wide chunks, immediately folded into FC2 accumulators.
#pragma unroll 1
    for (int hxb = 0; hxb < 256; hxb += 16) {
        float hv[16];
#pragma unroll
        for (int j = 0; j < 16; ++j) {
            const float* wr = w1 + (hxb + j) * 64;
            float a0 = bb1[hxb + j], a1 = 0.f, a2 = 0.f, a3 = 0.f;
#pragma unroll
            for (int c = 0; c < 64; c += 4) {
                a0 += wr[c + 0] * xv[c + 0];
                a1 += wr[c + 1] * xv[c + 1];
                a2 += wr[c + 2] * xv[c + 2];
                a3 += wr[c + 3] * xv[c + 3];
            }
            hv[j] = gelu_exact((a0 + a1) + (a2 + a3));
        }
#pragma unroll
        for (int o = 0; o < 64; ++o) {
            const float* wr2 = w2 + o * 256 + hxb;   // 16 contiguous floats
            float a0 = 0.f, a1 = 0.f;
#pragma unroll
            for (int j = 0; j < 16; j += 2) {
                a0 += wr2[j + 0] * hv[j + 0];
                a1 += wr2[j + 1] * hv[j + 1];
            }
            acc[o] += a0 + a1;
        }
    }

    // GELU + residual (re-read original x1 from io; only this thread's planes)
#pragma unroll
    for (int o = 0; o < 64; ++o) {
        float m = gelu_exact(acc[o]);
        iop[(size_t)o * HW] = iop[(size_t)o * HW] + m;
    }
}

// ---------------------------------------------------------------------------
extern "C" void kernel_launch(void* const* d_in, const int* in_sizes, int n_in,
                              void* d_out, int out_size, void* d_ws, size_t ws_size,
                              hipStream_t stream)
{
    const float* x     = (const float*)d_in[0];
    const float* g1    = (const float*)d_in[1];
    const float* b1    = (const float*)d_in[2];
    const float* g2    = (const float*)d_in[3];
    const float* b2    = (const float*)d_in[4];
    const float* w_qkv = (const float*)d_in[5];
    const float* b_qkv = (const float*)d_in[6];
    const float* w_out = (const float*)d_in[7];
    const float* b_out = (const float*)d_in[8];
    const float* w1    = (const float*)d_in[9];
    const float* bb1   = (const float*)d_in[10];
    const float* w2    = (const float*)d_in[11];
    const float* bb2   = (const float*)d_in[12];

    float* out = (float*)d_out;      // doubles as x1 storage (64 MiB)
    float* qkv = (float*)d_ws;       // 192 MiB scratch

    dim3 blk(256);
    dim3 grd(NPIX / 256);            // 1024 blocks

    k_ln_qkv<<<grd, blk, 0, stream>>>(x, g1, b1, w_qkv, b_qkv, qkv);
    k_attn  <<<grd, blk, 0, stream>>>(x, qkv, w_out, b_out, out);   // out = x1
    k_mlp   <<<grd, blk, 0, stream>>>(g2, b2, w1, bb1, w2, bb2, out);
}

// Round 3
// 557.688 us; speedup vs baseline: 4.3419x; 4.3419x over previous
//
#include <hip/hip_runtime.h>
#include <math.h>

#define HW    65536      // H*W
#define NPIX  262144     // B*H*W
#define EPSLN 1e-5f

typedef unsigned short ushort_t;
typedef __attribute__((ext_vector_type(8))) short bf16x8;
typedef __attribute__((ext_vector_type(4))) short bf16x4;
typedef __attribute__((ext_vector_type(4))) float f32x4;

// ws layout (ushort units): [0, QKV_USHORTS) = qkv bf16 [B][192][HW], then weights
#define QKV_USHORTS (4*192*65536)
#define WQ_H 0
#define WQ_L 12288
#define W1_H 24576
#define W1_L 40960
#define W2_H 57344
#define W2_L 73728
#define WO_H 90112
#define WO_L 94208
// total weights: 98304 ushorts (192 KiB); ws use = 96 MiB + 192 KiB < 192 MiB proven

__device__ __forceinline__ ushort_t f2bf(float f) {
    unsigned u = __float_as_uint(f);
    return (ushort_t)((u + 0x7FFFu + ((u >> 16) & 1u)) >> 16);   // RNE
}
__device__ __forceinline__ float bf2f(ushort_t h) {
    return __uint_as_float(((unsigned)h) << 16);
}
__device__ __forceinline__ float gelu_exact(float v) {
    return 0.5f * v * (1.f + erff(v * 0.70710678118654752f));
}

// ---------------------------------------------------------------------------
// Prep: split all weights into bf16 hi/lo (runs every launch; ws re-poisoned).
// ---------------------------------------------------------------------------
__global__ void k_prep(const float* __restrict__ wq, const float* __restrict__ w1,
                       const float* __restrict__ w2, const float* __restrict__ wo,
                       ushort_t* __restrict__ wb)
{
    int i = blockIdx.x * 256 + threadIdx.x;   // 0..49151
    float v; int oh, ol;
    if (i < 12288)      { v = wq[i];          oh = WQ_H + i;          ol = WQ_L + i; }
    else if (i < 28672) { int j = i - 12288;  v = w1[j]; oh = W1_H+j; ol = W1_L+j; }
    else if (i < 45056) { int j = i - 28672;  v = w2[j]; oh = W2_H+j; ol = W2_L+j; }
    else                { int j = i - 45056;  v = wo[j]; oh = WO_H+j; ol = WO_L+j; }
    ushort_t h = f2bf(v);
    wb[oh] = h;
    wb[ol] = f2bf(v - bf2f(h));
}

// ---------------------------------------------------------------------------
// Kernel 1: LN1 + QKV (64->192) via MFMA, wave-autonomous 16-px tiles.
// lane l: pixel q=l&15, channels (l>>4)*8+j (+{0,32}) == B-frag layout.
// qkv^T = Wqkv * xn^T; D: lane l reg i -> row mt*16+4g+i, col px q.
// Output stored bf16.
// ---------------------------------------------------------------------------
__global__ __launch_bounds__(256) void k_lnqkv_mfma(
    const float* __restrict__ x,  const float* __restrict__ g1,
    const float* __restrict__ b1, const ushort_t* __restrict__ wb,
    const float* __restrict__ bq, ushort_t* __restrict__ qkv)
{
    int tid = threadIdx.x, wave = tid >> 6, lane = tid & 63;
    int g = lane >> 4, q = lane & 15;
    int tile = blockIdx.x * 4 + wave;
    int px0 = tile * 16;
    int b = px0 >> 16;
    int hw = (px0 & 65535) + q;

    const float* xp = x + (size_t)b * 64 * HW + hw;
    float xv[16];
#pragma unroll
    for (int j = 0; j < 8; ++j) {
        xv[j]     = xp[(g * 8 + j) * HW];
        xv[8 + j] = xp[(32 + g * 8 + j) * HW];
    }
    float s = 0.f;
#pragma unroll
    for (int j = 0; j < 16; ++j) s += xv[j];
    s += __shfl_xor(s, 16); s += __shfl_xor(s, 32);
    float mu = s * 0.015625f;
    float s2 = 0.f;
#pragma unroll
    for (int j = 0; j < 16; ++j) { float d = xv[j] - mu; s2 += d * d; }
    s2 += __shfl_xor(s2, 16); s2 += __shfl_xor(s2, 32);
    float inv = rsqrtf(s2 * 0.015625f + EPSLN);

    bf16x8 bh[2], bl[2];
#pragma unroll
    for (int kt = 0; kt < 2; ++kt)
#pragma unroll
        for (int j = 0; j < 8; ++j) {
            int c = kt * 32 + g * 8 + j;
            float f = (xv[kt * 8 + j] - mu) * inv * g1[c] + b1[c];
            ushort_t h = f2bf(f);
            bh[kt][j] = (short)h;
            bl[kt][j] = (short)f2bf(f - bf2f(h));
        }

    const ushort_t* wqh = wb + WQ_H;
    const ushort_t* wql = wb + WQ_L;
    ushort_t* qp = qkv + (size_t)b * 192 * HW + hw;

#pragma unroll 1
    for (int mt = 0; mt < 12; ++mt) {
        f32x4 d;
#pragma unroll
        for (int i = 0; i < 4; ++i) d[i] = bq[mt * 16 + 4 * g + i];
#pragma unroll
        for (int kt = 0; kt < 2; ++kt) {
            bf16x8 ah = *(const bf16x8*)(wqh + (mt * 16 + q) * 64 + kt * 32 + g * 8);
            bf16x8 al = *(const bf16x8*)(wql + (mt * 16 + q) * 64 + kt * 32 + g * 8);
            d = __builtin_amdgcn_mfma_f32_16x16x32_bf16(ah, bh[kt], d, 0, 0, 0);
            d = __builtin_amdgcn_mfma_f32_16x16x32_bf16(ah, bl[kt], d, 0, 0, 0);
            d = __builtin_amdgcn_mfma_f32_16x16x32_bf16(al, bh[kt], d, 0, 0, 0);
        }
#pragma unroll
        for (int i = 0; i < 4; ++i)
            qp[(mt * 16 + 4 * g + i) * HW] = f2bf(d[i]);
    }
}

// ---------------------------------------------------------------------------
// Kernel 2: attention core (per-lane gather/softmax/PV, bf16 qkv) + MFMA
// out-proj + residual. Block = 1 wave = 64 pixels. attnout staged bf16 in
// LDS [64px][64ch] row=128B with 16B-chunk XOR swizzle (optimal 8/bank).
// ---------------------------------------------------------------------------
__global__ __launch_bounds__(64) void k_attn_mfma(
    const float* __restrict__ x, const ushort_t* __restrict__ qkv,
    const ushort_t* __restrict__ wb, const float* __restrict__ bo,
    float* __restrict__ x1)
{
    __shared__ ushort_t abuf[64 * 64];
    int lane = threadIdx.x;
    int px = blockIdx.x * 64 + lane;
    int b = px >> 16, hw = px & 65535;
    int hh = hw >> 8, ww = hw & 255;
    const ushort_t* base = qkv + (size_t)b * 192 * HW;

#pragma unroll 1
    for (int head = 0; head < 4; ++head) {
        float qv[16];
#pragma unroll
        for (int d = 0; d < 16; ++d)
            qv[d] = bf2f(base[(head * 16 + d) * HW + hw]) * 0.25f;

        float sc[9];
#pragma unroll
        for (int n = 0; n < 9; ++n) {
            int dy = (n / 3) * 2 - 2, dx = (n % 3) * 2 - 2;
            int y = hh + dy, xw = ww + dx;
            float s = 0.f;
            if (y >= 0 && y < 256 && xw >= 0 && xw < 256) {
                int nhw = y * 256 + xw;
                const ushort_t* kp = base + (64 + head * 16) * HW + nhw;
#pragma unroll
                for (int d = 0; d < 16; ++d) s += qv[d] * bf2f(kp[d * HW]);
            }
            sc[n] = s;
        }
        float mx = sc[0];
#pragma unroll
        for (int n = 1; n < 9; ++n) mx = fmaxf(mx, sc[n]);
        float sum = 0.f;
#pragma unroll
        for (int n = 0; n < 9; ++n) { sc[n] = __expf(sc[n] - mx); sum += sc[n]; }
        float isum = 1.f / sum;

        float o16[16];
#pragma unroll
        for (int d = 0; d < 16; ++d) o16[d] = 0.f;
#pragma unroll
        for (int n = 0; n < 9; ++n) {
            int dy = (n / 3) * 2 - 2, dx = (n % 3) * 2 - 2;
            int y = hh + dy, xw = ww + dx;
            if (y >= 0 && y < 256 && xw >= 0 && xw < 256) {
                float a = sc[n] * isum;
                int nhw = y * 256 + xw;
                const ushort_t* vp = base + (128 + head * 16) * HW + nhw;
#pragma unroll
                for (int d = 0; d < 16; ++d) o16[d] += a * bf2f(vp[d * HW]);
            }
        }
        bf16x8 v0, v1;
#pragma unroll
        for (int j = 0; j < 8; ++j) {
            v0[j] = (short)f2bf(o16[j]);
            v1[j] = (short)f2bf(o16[8 + j]);
        }
        int c0 = (head * 2)     ^ (lane & 7);
        int c1 = (head * 2 + 1) ^ (lane & 7);
        *(bf16x8*)(&abuf[lane * 64 + c0 * 8]) = v0;
        *(bf16x8*)(&abuf[lane * 64 + c1 * 8]) = v1;
    }
    __syncthreads();   // 1-wave block: just drains LDS writes

    int g = lane >> 4, q = lane & 15;
    const ushort_t* woh = wb + WO_H;
    const ushort_t* wol = wb + WO_L;

#pragma unroll 1
    for (int pg = 0; pg < 4; ++pg) {
        int r = pg * 16 + q;
        bf16x8 bb[2];
#pragma unroll
        for (int kt = 0; kt < 2; ++kt) {
            int c = (kt * 4 + g) ^ (r & 7);
            bb[kt] = *(const bf16x8*)(&abuf[r * 64 + c * 8]);
        }
        int hwg = (blockIdx.x * 64 + pg * 16 + q) & 65535;
#pragma unroll
        for (int mt = 0; mt < 4; ++mt) {
            f32x4 d;
#pragma unroll
            for (int i = 0; i < 4; ++i) d[i] = bo[mt * 16 + 4 * g + i];
#pragma unroll
            for (int kt = 0; kt < 2; ++kt) {
                bf16x8 ah = *(const bf16x8*)(woh + (mt * 16 + q) * 64 + kt * 32 + g * 8);
                bf16x8 al = *(const bf16x8*)(wol + (mt * 16 + q) * 64 + kt * 32 + g * 8);
                d = __builtin_amdgcn_mfma_f32_16x16x32_bf16(ah, bb[kt], d, 0, 0, 0);
                d = __builtin_amdgcn_mfma_f32_16x16x32_bf16(al, bb[kt], d, 0, 0, 0);
            }
#pragma unroll
            for (int i = 0; i < 4; ++i) {
                int o = mt * 16 + 4 * g + i;
                size_t idx = (size_t)(b * 64 + o) * HW + hwg;
                x1[idx] = x[idx] + d[i];     // x1 = x + proj(attn)
            }
        }
    }
}

// ---------------------------------------------------------------------------
// Kernel 3: fused MLP via MFMA: LN2 -> FC1(64->256)+GELU -> FC2(256->64)
// +GELU + residual. h lives only in a 2KB/wave LDS re-tile buffer
// ([16px][32h] bf16 hi+lo), consumed immediately by FC2 as B-frags.
// ---------------------------------------------------------------------------
__global__ __launch_bounds__(256) void k_mlp_mfma(
    const float* __restrict__ g2, const float* __restrict__ b2,
    const ushort_t* __restrict__ wb,
    const float* __restrict__ bb1, const float* __restrict__ bb2,
    float* __restrict__ io)
{
    __shared__ ushort_t hbh[4][512];
    __shared__ ushort_t hbl[4][512];
    int tid = threadIdx.x, wave = tid >> 6, lane = tid & 63;
    int g = lane >> 4, q = lane & 15;
    int tile = blockIdx.x * 4 + wave;
    int px0 = tile * 16;
    int b = px0 >> 16;
    int hw = (px0 & 65535) + q;
    float* iop = io + (size_t)b * 64 * HW + hw;

    float xv[16];
#pragma unroll
    for (int j = 0; j < 8; ++j) {
        xv[j]     = iop[(g * 8 + j) * HW];
        xv[8 + j] = iop[(32 + g * 8 + j) * HW];
    }
    float s = 0.f;
#pragma unroll
    for (int j = 0; j < 16; ++j) s += xv[j];
    s += __shfl_xor(s, 16); s += __shfl_xor(s, 32);
    float mu = s * 0.015625f;
    float s2 = 0.f;
#pragma unroll
    for (int j = 0; j < 16; ++j) { float d = xv[j] - mu; s2 += d * d; }
    s2 += __shfl_xor(s2, 16); s2 += __shfl_xor(s2, 32);
    float inv = rsqrtf(s2 * 0.015625f + EPSLN);

    bf16x8 bh[2], bl[2];
#pragma unroll
    for (int kt = 0; kt < 2; ++kt)
#pragma unroll
        for (int j = 0; j < 8; ++j) {
            int c = kt * 32 + g * 8 + j;
            float f = (xv[kt * 8 + j] - mu) * inv * g2[c] + b2[c];
            ushort_t h = f2bf(f);
            bh[kt][j] = (short)h;
            bl[kt][j] = (short)f2bf(f - bf2f(h));
        }

    const ushort_t* w1h = wb + W1_H;  const ushort_t* w1l = wb + W1_L;
    const ushort_t* w2h = wb + W2_H;  const ushort_t* w2l = wb + W2_L;

    f32x4 acc2[4];
#pragma unroll
    for (int m2 = 0; m2 < 4; ++m2)
#pragma unroll
        for (int i = 0; i < 4; ++i) acc2[m2][i] = bb2[m2 * 16 + 4 * g + i];

#pragma unroll 1
    for (int mtp = 0; mtp < 8; ++mtp) {
#pragma unroll
        for (int e = 0; e < 2; ++e) {
            int mt = mtp * 2 + e;
            f32x4 d;
#pragma unroll
            for (int i = 0; i < 4; ++i) d[i] = bb1[mt * 16 + 4 * g + i];
#pragma unroll
            for (int kt = 0; kt < 2; ++kt) {
                bf16x8 ah = *(const bf16x8*)(w1h + (mt * 16 + q) * 64 + kt * 32 + g * 8);
                bf16x8 al = *(const bf16x8*)(w1l + (mt * 16 + q) * 64 + kt * 32 + g * 8);
                d = __builtin_amdgcn_mfma_f32_16x16x32_bf16(ah, bh[kt], d, 0, 0, 0);
                d = __builtin_amdgcn_mfma_f32_16x16x32_bf16(ah, bl[kt], d, 0, 0, 0);
                d = __builtin_amdgcn_mfma_f32_16x16x32_bf16(al, bh[kt], d, 0, 0, 0);
            }
            bf16x4 vh, vl;
#pragma unroll
            for (int i = 0; i < 4; ++i) {
                float hv = gelu_exact(d[i]);
                ushort_t hh = f2bf(hv);
                vh[i] = (short)hh;
                vl[i] = (short)f2bf(hv - bf2f(hh));
            }
            *(bf16x4*)(&hbh[wave][q * 32 + e * 16 + g * 4]) = vh;
            *(bf16x4*)(&hbl[wave][q * 32 + e * 16 + g * 4]) = vl;
        }
        // FC2: consume this 32-h slice (kt2 == mtp)
        bf16x8 b2h = *(const bf16x8*)(&hbh[wave][q * 32 + g * 8]);
        bf16x8 b2l = *(const bf16x8*)(&hbl[wave][q * 32 + g * 8]);
#pragma unroll
        for (int m2 = 0; m2 < 4; ++m2) {
            bf16x8 ah = *(const bf16x8*)(w2h + (m2 * 16 + q) * 256 + mtp * 32 + g * 8);
            bf16x8 al = *(const bf16x8*)(w2l + (m2 * 16 + q) * 256 + mtp * 32 + g * 8);
            acc2[m2] = __builtin_amdgcn_mfma_f32_16x16x32_bf16(ah, b2h, acc2[m2], 0, 0, 0);
            acc2[m2] = __builtin_amdgcn_mfma_f32_16x16x32_bf16(ah, b2l, acc2[m2], 0, 0, 0);
            acc2[m2] = __builtin_amdgcn_mfma_f32_16x16x32_bf16(al, b2h, acc2[m2], 0, 0, 0);
        }
    }

#pragma unroll
    for (int m2 = 0; m2 < 4; ++m2)
#pragma unroll
        for (int i = 0; i < 4; ++i) {
            int o = m2 * 16 + 4 * g + i;
            float m = gelu_exact(acc2[m2][i]);
            iop[o * HW] = iop[o * HW] + m;
        }
}

// ---------------------------------------------------------------------------
extern "C" void kernel_launch(void* const* d_in, const int* in_sizes, int n_in,
                              void* d_out, int out_size, void* d_ws, size_t ws_size,
                              hipStream_t stream)
{
    const float* x     = (const float*)d_in[0];
    const float* g1    = (const float*)d_in[1];
    const float* b1    = (const float*)d_in[2];
    const float* g2    = (const float*)d_in[3];
    const float* b2    = (const float*)d_in[4];
    const float* w_qkv = (const float*)d_in[5];
    const float* b_qkv = (const float*)d_in[6];
    const float* w_out = (const float*)d_in[7];
    const float* b_out = (const float*)d_in[8];
    const float* w1    = (const float*)d_in[9];
    const float* bb1   = (const float*)d_in[10];
    const float* w2    = (const float*)d_in[11];
    const float* bb2   = (const float*)d_in[12];

    float*    out = (float*)d_out;             // x1, then final output (in place)
    ushort_t* qkv = (ushort_t*)d_ws;           // bf16 qkv, 96 MiB
    ushort_t* wb  = (ushort_t*)d_ws + QKV_USHORTS;   // bf16 hi/lo weights

    k_prep      <<<192,  256, 0, stream>>>(w_qkv, w1, w2, w_out, wb);
    k_lnqkv_mfma<<<4096, 256, 0, stream>>>(x, g1, b1, wb, b_qkv, qkv);
    k_attn_mfma <<<4096,  64, 0, stream>>>(x, qkv, wb, b_out, out);
    k_mlp_mfma  <<<4096, 256, 0, stream>>>(g2, b2, wb, bb1, bb2, out);
}

// Round 4
// 396.260 us; speedup vs baseline: 6.1106x; 1.4074x over previous
//
#include <hip/hip_runtime.h>
#include <math.h>

#define HW    65536      // H*W
#define NPIX  262144     // B*H*W
#define EPSLN 1e-5f

typedef unsigned short ushort_t;
typedef __attribute__((ext_vector_type(8))) short bf16x8;
typedef __attribute__((ext_vector_type(4))) short bf16x4;
typedef __attribute__((ext_vector_type(4))) float f32x4;

// ws layout (ushort units): [0, QKV_USHORTS) = qkv bf16 [B][12][HW][16], then weights
#define QKV_USHORTS (4*192*65536)
#define WQ_H 0
#define WQ_L 12288
#define W1_H 24576
#define W1_L 40960
#define W2_H 57344
#define W2_L 73728
#define WO_H 90112
#define WO_L 94208

__device__ __forceinline__ ushort_t f2bf(float f) {
    unsigned u = __float_as_uint(f);
    return (ushort_t)((u + 0x7FFFu + ((u >> 16) & 1u)) >> 16);   // RNE
}
__device__ __forceinline__ float bf2f(ushort_t h) {
    return __uint_as_float(((unsigned)h) << 16);
}
// A&S 7.1.26 erf, |err| <= 1.5e-7 — replaces libm erff (~25 ops -> ~14)
__device__ __forceinline__ float gelu_fast(float v) {
    float z  = v * 0.70710678118654752f;
    float az = fabsf(z);
    float t  = __builtin_amdgcn_rcpf(1.f + 0.3275911f * az);
    float p  = t * (0.254829592f + t * (-0.284496736f +
               t * (1.421413741f + t * (-1.453152027f + t * 1.061405429f))));
    float e  = __expf(-az * az);
    float er = 1.f - p * e;
    er = copysignf(er, z);
    return 0.5f * v * (1.f + er);
}

// ---------------------------------------------------------------------------
// Prep: split all weights into bf16 hi/lo.
// ---------------------------------------------------------------------------
__global__ void k_prep(const float* __restrict__ wq, const float* __restrict__ w1,
                       const float* __restrict__ w2, const float* __restrict__ wo,
                       ushort_t* __restrict__ wb)
{
    int i = blockIdx.x * 256 + threadIdx.x;   // 0..49151
    float v; int oh, ol;
    if (i < 12288)      { v = wq[i];          oh = WQ_H + i;          ol = WQ_L + i; }
    else if (i < 28672) { int j = i - 12288;  v = w1[j]; oh = W1_H+j; ol = W1_L+j; }
    else if (i < 45056) { int j = i - 28672;  v = w2[j]; oh = W2_H+j; ol = W2_L+j; }
    else                { int j = i - 45056;  v = wo[j]; oh = WO_H+j; ol = WO_L+j; }
    ushort_t h = f2bf(v);
    wb[oh] = h;
    wb[ol] = f2bf(v - bf2f(h));
}

// ---------------------------------------------------------------------------
// Kernel 1: LN1 + QKV (64->192) via MFMA. 32 px per wave (2 pixel-frags per
// weight fragment). qkv stored bf16 as [B][12 tiles][HW][16 d] (d-contiguous).
// ---------------------------------------------------------------------------
__global__ __launch_bounds__(256) void k_lnqkv_mfma(
    const float* __restrict__ x,  const float* __restrict__ g1,
    const float* __restrict__ b1, const ushort_t* __restrict__ wb,
    const float* __restrict__ bq, ushort_t* __restrict__ qkv)
{
    int tid = threadIdx.x, wave = tid >> 6, lane = tid & 63;
    int g = lane >> 4, q = lane & 15;
    int wgl = blockIdx.x * 4 + wave;        // 0..8191
    int px0 = wgl * 32;
    int b   = px0 >> 16;
    int hwb = px0 & 65535;

    bf16x8 bh[2][2], bl[2][2];
#pragma unroll
    for (int pg = 0; pg < 2; ++pg) {
        int hw = hwb + pg * 16 + q;
        const float* xp = x + (size_t)b * 64 * HW + hw;
        float xv[16];
#pragma unroll
        for (int j = 0; j < 8; ++j) {
            xv[j]     = xp[(g * 8 + j) * HW];
            xv[8 + j] = xp[(32 + g * 8 + j) * HW];
        }
        float s = 0.f;
#pragma unroll
        for (int j = 0; j < 16; ++j) s += xv[j];
        s += __shfl_xor(s, 16); s += __shfl_xor(s, 32);
        float mu = s * 0.015625f;
        float s2 = 0.f;
#pragma unroll
        for (int j = 0; j < 16; ++j) { float d = xv[j] - mu; s2 += d * d; }
        s2 += __shfl_xor(s2, 16); s2 += __shfl_xor(s2, 32);
        float inv = rsqrtf(s2 * 0.015625f + EPSLN);
#pragma unroll
        for (int kt = 0; kt < 2; ++kt)
#pragma unroll
            for (int j = 0; j < 8; ++j) {
                int c = kt * 32 + g * 8 + j;
                float f = (xv[kt * 8 + j] - mu) * inv * g1[c] + b1[c];
                ushort_t h = f2bf(f);
                bh[pg][kt][j] = (short)h;
                bl[pg][kt][j] = (short)f2bf(f - bf2f(h));
            }
    }

    const ushort_t* wqh = wb + WQ_H;
    const ushort_t* wql = wb + WQ_L;
    ushort_t* outb = qkv + (size_t)b * 12 * HW * 16;

#pragma unroll 2
    for (int mt = 0; mt < 12; ++mt) {
        bf16x8 ah[2], al[2];
#pragma unroll
        for (int kt = 0; kt < 2; ++kt) {
            ah[kt] = *(const bf16x8*)(wqh + (mt * 16 + q) * 64 + kt * 32 + g * 8);
            al[kt] = *(const bf16x8*)(wql + (mt * 16 + q) * 64 + kt * 32 + g * 8);
        }
#pragma unroll
        for (int pg = 0; pg < 2; ++pg) {
            f32x4 d;
#pragma unroll
            for (int i = 0; i < 4; ++i) d[i] = bq[mt * 16 + 4 * g + i];
#pragma unroll
            for (int kt = 0; kt < 2; ++kt) {
                d = __builtin_amdgcn_mfma_f32_16x16x32_bf16(ah[kt], bh[pg][kt], d, 0, 0, 0);
                d = __builtin_amdgcn_mfma_f32_16x16x32_bf16(ah[kt], bl[pg][kt], d, 0, 0, 0);
                d = __builtin_amdgcn_mfma_f32_16x16x32_bf16(al[kt], bh[pg][kt], d, 0, 0, 0);
            }
            bf16x4 st;
#pragma unroll
            for (int i = 0; i < 4; ++i) st[i] = (short)f2bf(d[i]);
            int hw = hwb + pg * 16 + q;
            *(bf16x4*)(outb + ((size_t)mt * HW + hw) * 16 + 4 * g) = st;
        }
    }
}

// ---------------------------------------------------------------------------
// Kernel 2: neighborhood attention with d-contiguous bf16 K/V (2x bf16x8 per
// neighbor) + MFMA out-proj + residual. Block = 1 wave = 64 pixels.
// ---------------------------------------------------------------------------
__global__ __launch_bounds__(64) void k_attn_mfma(
    const float* __restrict__ x, const ushort_t* __restrict__ qkv,
    const ushort_t* __restrict__ wb, const float* __restrict__ bo,
    float* __restrict__ x1)
{
    __shared__ ushort_t abuf[64 * 64];
    int lane = threadIdx.x;
    int px = blockIdx.x * 64 + lane;
    int b = px >> 16, hw = px & 65535;
    int hh = hw >> 8, ww = hw & 255;
    const ushort_t* tb = qkv + (size_t)b * 12 * HW * 16;

#pragma unroll 1
    for (int head = 0; head < 4; ++head) {
        const ushort_t* qp = tb + ((size_t)head * HW + hw) * 16;
        bf16x8 q0 = *(const bf16x8*)qp;
        bf16x8 q1 = *(const bf16x8*)(qp + 8);
        float qv[16];
#pragma unroll
        for (int j = 0; j < 8; ++j) {
            qv[j]     = bf2f((ushort_t)q0[j]) * 0.25f;
            qv[8 + j] = bf2f((ushort_t)q1[j]) * 0.25f;
        }
        const ushort_t* kb = tb + (size_t)(4 + head) * HW * 16;
        const ushort_t* vb = tb + (size_t)(8 + head) * HW * 16;

        float sc[9];
#pragma unroll
        for (int n = 0; n < 9; ++n) {
            int dy = (n / 3) * 2 - 2, dx = (n % 3) * 2 - 2;
            int y = hh + dy, xw = ww + dx;
            float s = 0.f;
            if (y >= 0 && y < 256 && xw >= 0 && xw < 256) {
                const ushort_t* kp = kb + (size_t)(y * 256 + xw) * 16;
                bf16x8 k0 = *(const bf16x8*)kp;
                bf16x8 k1 = *(const bf16x8*)(kp + 8);
#pragma unroll
                for (int j = 0; j < 8; ++j) {
                    s += qv[j]     * bf2f((ushort_t)k0[j]);
                    s += qv[8 + j] * bf2f((ushort_t)k1[j]);
                }
            }
            sc[n] = s;
        }
        float mx = sc[0];
#pragma unroll
        for (int n = 1; n < 9; ++n) mx = fmaxf(mx, sc[n]);

        float sum = 0.f;
        float o16[16];
#pragma unroll
        for (int d = 0; d < 16; ++d) o16[d] = 0.f;
#pragma unroll
        for (int n = 0; n < 9; ++n) {
            int dy = (n / 3) * 2 - 2, dx = (n % 3) * 2 - 2;
            int y = hh + dy, xw = ww + dx;
            float e = __expf(sc[n] - mx);
            sum += e;
            if (y >= 0 && y < 256 && xw >= 0 && xw < 256) {
                const ushort_t* vp = vb + (size_t)(y * 256 + xw) * 16;
                bf16x8 v0 = *(const bf16x8*)vp;
                bf16x8 v1 = *(const bf16x8*)(vp + 8);
#pragma unroll
                for (int j = 0; j < 8; ++j) {
                    o16[j]     += e * bf2f((ushort_t)v0[j]);
                    o16[8 + j] += e * bf2f((ushort_t)v1[j]);
                }
            }
        }
        float isum = __builtin_amdgcn_rcpf(sum);

        bf16x8 w0, w1v;
#pragma unroll
        for (int j = 0; j < 8; ++j) {
            w0[j]  = (short)f2bf(o16[j] * isum);
            w1v[j] = (short)f2bf(o16[8 + j] * isum);
        }
        int c0 = (head * 2)     ^ (lane & 7);
        int c1 = (head * 2 + 1) ^ (lane & 7);
        *(bf16x8*)(&abuf[lane * 64 + c0 * 8]) = w0;
        *(bf16x8*)(&abuf[lane * 64 + c1 * 8]) = w1v;
    }
    __syncthreads();

    int g = lane >> 4, q = lane & 15;
    const ushort_t* woh = wb + WO_H;
    const ushort_t* wol = wb + WO_L;

#pragma unroll 1
    for (int pg = 0; pg < 4; ++pg) {
        int r = pg * 16 + q;
        bf16x8 bb[2];
#pragma unroll
        for (int kt = 0; kt < 2; ++kt) {
            int c = (kt * 4 + g) ^ (r & 7);
            bb[kt] = *(const bf16x8*)(&abuf[r * 64 + c * 8]);
        }
        int hwg = (blockIdx.x * 64 + pg * 16 + q) & 65535;
#pragma unroll
        for (int mt = 0; mt < 4; ++mt) {
            f32x4 d;
#pragma unroll
            for (int i = 0; i < 4; ++i) d[i] = bo[mt * 16 + 4 * g + i];
#pragma unroll
            for (int kt = 0; kt < 2; ++kt) {
                bf16x8 ah = *(const bf16x8*)(woh + (mt * 16 + q) * 64 + kt * 32 + g * 8);
                bf16x8 al = *(const bf16x8*)(wol + (mt * 16 + q) * 64 + kt * 32 + g * 8);
                d = __builtin_amdgcn_mfma_f32_16x16x32_bf16(ah, bb[kt], d, 0, 0, 0);
                d = __builtin_amdgcn_mfma_f32_16x16x32_bf16(al, bb[kt], d, 0, 0, 0);
            }
#pragma unroll
            for (int i = 0; i < 4; ++i) {
                int o = mt * 16 + 4 * g + i;
                size_t idx = (size_t)(b * 64 + o) * HW + hwg;
                x1[idx] = x[idx] + d[i];
            }
        }
    }
}

// ---------------------------------------------------------------------------
// Kernel 3: fused MLP via MFMA, 32 px per wave. h re-tiled through a small
// LDS buffer with order-preserving chunk-XOR swizzle (^(q&6)).
// ---------------------------------------------------------------------------
__global__ __launch_bounds__(256) void k_mlp_mfma(
    const float* __restrict__ g2, const float* __restrict__ b2,
    const ushort_t* __restrict__ wb,
    const float* __restrict__ bb1, const float* __restrict__ bb2,
    float* __restrict__ io)
{
    __shared__ ushort_t hbh[4][2][512];
    __shared__ ushort_t hbl[4][2][512];
    int tid = threadIdx.x, wave = tid >> 6, lane = tid & 63;
    int g = lane >> 4, q = lane & 15;
    int wgl = blockIdx.x * 4 + wave;
    int px0 = wgl * 32;
    int b   = px0 >> 16;
    int hwb = px0 & 65535;
    float* iob = io + (size_t)b * 64 * HW;

    bf16x8 bh[2][2], bl[2][2];
#pragma unroll
    for (int pg = 0; pg < 2; ++pg) {
        int hw = hwb + pg * 16 + q;
        const float* xp = iob + hw;
        float xv[16];
#pragma unroll
        for (int j = 0; j < 8; ++j) {
            xv[j]     = xp[(g * 8 + j) * HW];
            xv[8 + j] = xp[(32 + g * 8 + j) * HW];
        }
        float s = 0.f;
#pragma unroll
        for (int j = 0; j < 16; ++j) s += xv[j];
        s += __shfl_xor(s, 16); s += __shfl_xor(s, 32);
        float mu = s * 0.015625f;
        float s2 = 0.f;
#pragma unroll
        for (int j = 0; j < 16; ++j) { float d = xv[j] - mu; s2 += d * d; }
        s2 += __shfl_xor(s2, 16); s2 += __shfl_xor(s2, 32);
        float inv = rsqrtf(s2 * 0.015625f + EPSLN);
#pragma unroll
        for (int kt = 0; kt < 2; ++kt)
#pragma unroll
            for (int j = 0; j < 8; ++j) {
                int c = kt * 32 + g * 8 + j;
                float f = (xv[kt * 8 + j] - mu) * inv * g2[c] + b2[c];
                ushort_t h = f2bf(f);
                bh[pg][kt][j] = (short)h;
                bl[pg][kt][j] = (short)f2bf(f - bf2f(h));
            }
    }

    const ushort_t* w1h = wb + W1_H;  const ushort_t* w1l = wb + W1_L;
    const ushort_t* w2h = wb + W2_H;  const ushort_t* w2l = wb + W2_L;

    f32x4 acc2[2][4];
#pragma unroll
    for (int pg = 0; pg < 2; ++pg)
#pragma unroll
        for (int m2 = 0; m2 < 4; ++m2)
#pragma unroll
            for (int i = 0; i < 4; ++i) acc2[pg][m2][i] = bb2[m2 * 16 + 4 * g + i];

#pragma unroll 1
    for (int mtp = 0; mtp < 8; ++mtp) {
#pragma unroll
        for (int e = 0; e < 2; ++e) {
            int mt = mtp * 2 + e;
            bf16x8 ah[2], al[2];
#pragma unroll
            for (int kt = 0; kt < 2; ++kt) {
                ah[kt] = *(const bf16x8*)(w1h + (mt * 16 + q) * 64 + kt * 32 + g * 8);
                al[kt] = *(const bf16x8*)(w1l + (mt * 16 + q) * 64 + kt * 32 + g * 8);
            }
#pragma unroll
            for (int pg = 0; pg < 2; ++pg) {
                f32x4 d;
#pragma unroll
                for (int i = 0; i < 4; ++i) d[i] = bb1[mt * 16 + 4 * g + i];
#pragma unroll
                for (int kt = 0; kt < 2; ++kt) {
                    d = __builtin_amdgcn_mfma_f32_16x16x32_bf16(ah[kt], bh[pg][kt], d, 0, 0, 0);
                    d = __builtin_amdgcn_mfma_f32_16x16x32_bf16(ah[kt], bl[pg][kt], d, 0, 0, 0);
                    d = __builtin_amdgcn_mfma_f32_16x16x32_bf16(al[kt], bh[pg][kt], d, 0, 0, 0);
                }
                bf16x4 vh, vl;
#pragma unroll
                for (int i = 0; i < 4; ++i) {
                    float hv = gelu_fast(d[i]);
                    ushort_t hh = f2bf(hv);
                    vh[i] = (short)hh;
                    vl[i] = (short)f2bf(hv - bf2f(hh));
                }
                int chunk = (e * 4 + g) ^ (q & 6);
                *(bf16x4*)(&hbh[wave][pg][q * 32 + chunk * 4]) = vh;
                *(bf16x4*)(&hbl[wave][pg][q * 32 + chunk * 4]) = vl;
            }
        }
        // FC2: consume this 32-h slice
        bf16x8 p2h[2], p2l[2];
#pragma unroll
        for (int pg = 0; pg < 2; ++pg) {
            int c0 = (2 * g) ^ (q & 6);
            p2h[pg] = *(const bf16x8*)(&hbh[wave][pg][q * 32 + c0 * 4]);
            p2l[pg] = *(const bf16x8*)(&hbl[wave][pg][q * 32 + c0 * 4]);
        }
#pragma unroll
        for (int m2 = 0; m2 < 4; ++m2) {
            bf16x8 ah2 = *(const bf16x8*)(w2h + (m2 * 16 + q) * 256 + mtp * 32 + g * 8);
            bf16x8 al2 = *(const bf16x8*)(w2l + (m2 * 16 + q) * 256 + mtp * 32 + g * 8);
#pragma unroll
            for (int pg = 0; pg < 2; ++pg) {
                acc2[pg][m2] = __builtin_amdgcn_mfma_f32_16x16x32_bf16(ah2, p2h[pg], acc2[pg][m2], 0, 0, 0);
                acc2[pg][m2] = __builtin_amdgcn_mfma_f32_16x16x32_bf16(ah2, p2l[pg], acc2[pg][m2], 0, 0, 0);
                acc2[pg][m2] = __builtin_amdgcn_mfma_f32_16x16x32_bf16(al2, p2h[pg], acc2[pg][m2], 0, 0, 0);
            }
        }
    }

#pragma unroll
    for (int pg = 0; pg < 2; ++pg)
#pragma unroll
        for (int m2 = 0; m2 < 4; ++m2)
#pragma unroll
            for (int i = 0; i < 4; ++i) {
                int o = m2 * 16 + 4 * g + i;
                int hw = hwb + pg * 16 + q;
                float m = gelu_fast(acc2[pg][m2][i]);
                iob[(size_t)o * HW + hw] = iob[(size_t)o * HW + hw] + m;
            }
}

// ---------------------------------------------------------------------------
extern "C" void kernel_launch(void* const* d_in, const int* in_sizes, int n_in,
                              void* d_out, int out_size, void* d_ws, size_t ws_size,
                              hipStream_t stream)
{
    const float* x     = (const float*)d_in[0];
    const float* g1    = (const float*)d_in[1];
    const float* b1    = (const float*)d_in[2];
    const float* g2    = (const float*)d_in[3];
    const float* b2    = (const float*)d_in[4];
    const float* w_qkv = (const float*)d_in[5];
    const float* b_qkv = (const float*)d_in[6];
    const float* w_out = (const float*)d_in[7];
    const float* b_out = (const float*)d_in[8];
    const float* w1    = (const float*)d_in[9];
    const float* bb1   = (const float*)d_in[10];
    const float* w2    = (const float*)d_in[11];
    const float* bb2   = (const float*)d_in[12];

    float*    out = (float*)d_out;                   // x1, then final (in place)
    ushort_t* qkv = (ushort_t*)d_ws;                 // bf16 qkv, 96 MiB
    ushort_t* wb  = (ushort_t*)d_ws + QKV_USHORTS;   // bf16 hi/lo weights

    k_prep      <<<192,  256, 0, stream>>>(w_qkv, w1, w2, w_out, wb);
    k_lnqkv_mfma<<<2048, 256, 0, stream>>>(x, g1, b1, wb, b_qkv, qkv);
    k_attn_mfma <<<4096,  64, 0, stream>>>(x, qkv, wb, b_out, out);
    k_mlp_mfma  <<<2048, 256, 0, stream>>>(g2, b2, wb, bb1, bb2, out);
}

// Round 5
// 390.814 us; speedup vs baseline: 6.1958x; 1.0139x over previous
//
#include <hip/hip_runtime.h>
#include <math.h>

#define HW    65536      // H*W
#define NPIX  262144     // B*H*W
#define EPSLN 1e-5f

typedef unsigned short ushort_t;
typedef __attribute__((ext_vector_type(8))) short bf16x8;
typedef __attribute__((ext_vector_type(4))) short bf16x4;
typedef __attribute__((ext_vector_type(4))) float f32x4;

// ws layout (ushort units): [0, QKV_USHORTS) = qkv bf16 [B][12][HW][16], then weights
#define QKV_USHORTS (4*192*65536)
#define WQ_H 0
#define WQ_L 12288
#define W1_H 24576
#define W1_L 40960
#define W2_H 57344
#define W2_L 73728
#define WO_H 90112
#define WO_L 94208

__device__ __forceinline__ ushort_t f2bf(float f) {
    unsigned u = __float_as_uint(f);
    return (ushort_t)((u + 0x7FFFu + ((u >> 16) & 1u)) >> 16);   // RNE
}
__device__ __forceinline__ float bf2f(ushort_t h) {
    return __uint_as_float(((unsigned)h) << 16);
}
// A&S 7.1.26 erf, |err| <= 1.5e-7
__device__ __forceinline__ float gelu_fast(float v) {
    float z  = v * 0.70710678118654752f;
    float az = fabsf(z);
    float t  = __builtin_amdgcn_rcpf(1.f + 0.3275911f * az);
    float p  = t * (0.254829592f + t * (-0.284496736f +
               t * (1.421413741f + t * (-1.453152027f + t * 1.061405429f))));
    float e  = __expf(-az * az);
    float er = 1.f - p * e;
    er = copysignf(er, z);
    return 0.5f * v * (1.f + er);
}

// ---------------------------------------------------------------------------
// Prep: split all weights into bf16 hi/lo.
// ---------------------------------------------------------------------------
__global__ void k_prep(const float* __restrict__ wq, const float* __restrict__ w1,
                       const float* __restrict__ w2, const float* __restrict__ wo,
                       ushort_t* __restrict__ wb)
{
    int i = blockIdx.x * 256 + threadIdx.x;   // 0..49151
    float v; int oh, ol;
    if (i < 12288)      { v = wq[i];          oh = WQ_H + i;          ol = WQ_L + i; }
    else if (i < 28672) { int j = i - 12288;  v = w1[j]; oh = W1_H+j; ol = W1_L+j; }
    else if (i < 45056) { int j = i - 28672;  v = w2[j]; oh = W2_H+j; ol = W2_L+j; }
    else                { int j = i - 45056;  v = wo[j]; oh = WO_H+j; ol = WO_L+j; }
    ushort_t h = f2bf(v);
    wb[oh] = h;
    wb[ol] = f2bf(v - bf2f(h));
}

// ---------------------------------------------------------------------------
// Kernel 1: LN1 + QKV (64->192) via MFMA, 32 px/wave, 2-MFMA hi/lo weights
// (activation single bf16). qkv stored bf16 [B][12][HW][16] d-contiguous.
// ---------------------------------------------------------------------------
__global__ __launch_bounds__(256) void k_lnqkv_mfma(
    const float* __restrict__ x,  const float* __restrict__ g1,
    const float* __restrict__ b1, const ushort_t* __restrict__ wb,
    const float* __restrict__ bq, ushort_t* __restrict__ qkv)
{
    int tid = threadIdx.x, wave = tid >> 6, lane = tid & 63;
    int g = lane >> 4, q = lane & 15;
    int wgl = blockIdx.x * 4 + wave;
    int px0 = wgl * 32;
    int b   = px0 >> 16;
    int hwb = px0 & 65535;

    bf16x8 bh[2][2];
#pragma unroll
    for (int pg = 0; pg < 2; ++pg) {
        int hw = hwb + pg * 16 + q;
        const float* xp = x + (size_t)b * 64 * HW + hw;
        float xv[16];
#pragma unroll
        for (int j = 0; j < 8; ++j) {
            xv[j]     = xp[(g * 8 + j) * HW];
            xv[8 + j] = xp[(32 + g * 8 + j) * HW];
        }
        float s = 0.f;
#pragma unroll
        for (int j = 0; j < 16; ++j) s += xv[j];
        s += __shfl_xor(s, 16); s += __shfl_xor(s, 32);
        float mu = s * 0.015625f;
        float s2 = 0.f;
#pragma unroll
        for (int j = 0; j < 16; ++j) { float d = xv[j] - mu; s2 += d * d; }
        s2 += __shfl_xor(s2, 16); s2 += __shfl_xor(s2, 32);
        float inv = rsqrtf(s2 * 0.015625f + EPSLN);
#pragma unroll
        for (int kt = 0; kt < 2; ++kt)
#pragma unroll
            for (int j = 0; j < 8; ++j) {
                int c = kt * 32 + g * 8 + j;
                float f = (xv[kt * 8 + j] - mu) * inv * g1[c] + b1[c];
                bh[pg][kt][j] = (short)f2bf(f);
            }
    }

    const ushort_t* wqh = wb + WQ_H;
    const ushort_t* wql = wb + WQ_L;
    ushort_t* outb = qkv + (size_t)b * 12 * HW * 16;

#pragma unroll 2
    for (int mt = 0; mt < 12; ++mt) {
        bf16x8 ah[2], al[2];
#pragma unroll
        for (int kt = 0; kt < 2; ++kt) {
            ah[kt] = *(const bf16x8*)(wqh + (mt * 16 + q) * 64 + kt * 32 + g * 8);
            al[kt] = *(const bf16x8*)(wql + (mt * 16 + q) * 64 + kt * 32 + g * 8);
        }
#pragma unroll
        for (int pg = 0; pg < 2; ++pg) {
            f32x4 d;
#pragma unroll
            for (int i = 0; i < 4; ++i) d[i] = bq[mt * 16 + 4 * g + i];
#pragma unroll
            for (int kt = 0; kt < 2; ++kt) {
                d = __builtin_amdgcn_mfma_f32_16x16x32_bf16(ah[kt], bh[pg][kt], d, 0, 0, 0);
                d = __builtin_amdgcn_mfma_f32_16x16x32_bf16(al[kt], bh[pg][kt], d, 0, 0, 0);
            }
            bf16x4 st;
#pragma unroll
            for (int i = 0; i < 4; ++i) st[i] = (short)f2bf(d[i]);
            int hw = hwb + pg * 16 + q;
            *(bf16x4*)(outb + ((size_t)mt * HW + hw) * 16 + 4 * g) = st;
        }
    }
}

// ---------------------------------------------------------------------------
// Kernel 2: neighborhood attention, 4 waves/block (256 px), per-wave abuf.
// d-contiguous bf16 K/V gathers + MFMA out-proj + residual.
// ---------------------------------------------------------------------------
__global__ __launch_bounds__(256) void k_attn_mfma(
    const float* __restrict__ x, const ushort_t* __restrict__ qkv,
    const ushort_t* __restrict__ wb, const float* __restrict__ bo,
    float* __restrict__ x1)
{
    __shared__ ushort_t abuf[4][64 * 64];
    int tid = threadIdx.x, wave = tid >> 6, lane = tid & 63;
    int px = blockIdx.x * 256 + tid;
    int b = px >> 16, hw = px & 65535;
    int hh = hw >> 8, ww = hw & 255;
    const ushort_t* tb = qkv + (size_t)b * 12 * HW * 16;

#pragma unroll 1
    for (int head = 0; head < 4; ++head) {
        const ushort_t* qp = tb + ((size_t)head * HW + hw) * 16;
        bf16x8 q0 = *(const bf16x8*)qp;
        bf16x8 q1 = *(const bf16x8*)(qp + 8);
        float qv[16];
#pragma unroll
        for (int j = 0; j < 8; ++j) {
            qv[j]     = bf2f((ushort_t)q0[j]) * 0.25f;
            qv[8 + j] = bf2f((ushort_t)q1[j]) * 0.25f;
        }
        const ushort_t* kb = tb + (size_t)(4 + head) * HW * 16;
        const ushort_t* vb = tb + (size_t)(8 + head) * HW * 16;

        float sc[9];
#pragma unroll
        for (int n = 0; n < 9; ++n) {
            int dy = (n / 3) * 2 - 2, dx = (n % 3) * 2 - 2;
            int y = hh + dy, xw = ww + dx;
            float s = 0.f;
            if (y >= 0 && y < 256 && xw >= 0 && xw < 256) {
                const ushort_t* kp = kb + (size_t)(y * 256 + xw) * 16;
                bf16x8 k0 = *(const bf16x8*)kp;
                bf16x8 k1 = *(const bf16x8*)(kp + 8);
#pragma unroll
                for (int j = 0; j < 8; ++j) {
                    s += qv[j]     * bf2f((ushort_t)k0[j]);
                    s += qv[8 + j] * bf2f((ushort_t)k1[j]);
                }
            }
            sc[n] = s;
        }
        float mx = sc[0];
#pragma unroll
        for (int n = 1; n < 9; ++n) mx = fmaxf(mx, sc[n]);

        float sum = 0.f;
        float o16[16];
#pragma unroll
        for (int d = 0; d < 16; ++d) o16[d] = 0.f;
#pragma unroll
        for (int n = 0; n < 9; ++n) {
            int dy = (n / 3) * 2 - 2, dx = (n % 3) * 2 - 2;
            int y = hh + dy, xw = ww + dx;
            float e = __expf(sc[n] - mx);
            sum += e;
            if (y >= 0 && y < 256 && xw >= 0 && xw < 256) {
                const ushort_t* vp = vb + (size_t)(y * 256 + xw) * 16;
                bf16x8 v0 = *(const bf16x8*)vp;
                bf16x8 v1 = *(const bf16x8*)(vp + 8);
#pragma unroll
                for (int j = 0; j < 8; ++j) {
                    o16[j]     += e * bf2f((ushort_t)v0[j]);
                    o16[8 + j] += e * bf2f((ushort_t)v1[j]);
                }
            }
        }
        float isum = __builtin_amdgcn_rcpf(sum);

        bf16x8 w0, w1v;
#pragma unroll
        for (int j = 0; j < 8; ++j) {
            w0[j]  = (short)f2bf(o16[j] * isum);
            w1v[j] = (short)f2bf(o16[8 + j] * isum);
        }
        int c0 = (head * 2)     ^ (lane & 7);
        int c1 = (head * 2 + 1) ^ (lane & 7);
        *(bf16x8*)(&abuf[wave][lane * 64 + c0 * 8]) = w0;
        *(bf16x8*)(&abuf[wave][lane * 64 + c1 * 8]) = w1v;
    }
    __syncthreads();

    int g = lane >> 4, q = lane & 15;
    const ushort_t* woh = wb + WO_H;
    const ushort_t* wol = wb + WO_L;
    int pxw = blockIdx.x * 256 + wave * 64;    // wave's pixel base
    int hwwb = pxw & 65535;

#pragma unroll 1
    for (int pg = 0; pg < 4; ++pg) {
        int r = pg * 16 + q;
        bf16x8 bb[2];
#pragma unroll
        for (int kt = 0; kt < 2; ++kt) {
            int c = (kt * 4 + g) ^ (r & 7);
            bb[kt] = *(const bf16x8*)(&abuf[wave][r * 64 + c * 8]);
        }
        int hwg = hwwb + pg * 16 + q;
#pragma unroll
        for (int mt = 0; mt < 4; ++mt) {
            f32x4 d;
#pragma unroll
            for (int i = 0; i < 4; ++i) d[i] = bo[mt * 16 + 4 * g + i];
#pragma unroll
            for (int kt = 0; kt < 2; ++kt) {
                bf16x8 ah = *(const bf16x8*)(woh + (mt * 16 + q) * 64 + kt * 32 + g * 8);
                bf16x8 al = *(const bf16x8*)(wol + (mt * 16 + q) * 64 + kt * 32 + g * 8);
                d = __builtin_amdgcn_mfma_f32_16x16x32_bf16(ah, bb[kt], d, 0, 0, 0);
                d = __builtin_amdgcn_mfma_f32_16x16x32_bf16(al, bb[kt], d, 0, 0, 0);
            }
#pragma unroll
            for (int i = 0; i < 4; ++i) {
                int o = mt * 16 + 4 * g + i;
                size_t idx = (size_t)(b * 64 + o) * HW + hwg;
                x1[idx] = x[idx] + d[i];
            }
        }
    }
}

// ---------------------------------------------------------------------------
// Kernel 3: fused MLP via MFMA, 32 px/wave, 2-MFMA hi/lo weights, h single
// bf16 through the LDS re-tile (8 KB/block).
// ---------------------------------------------------------------------------
__global__ __launch_bounds__(256) void k_mlp_mfma(
    const float* __restrict__ g2, const float* __restrict__ b2,
    const ushort_t* __restrict__ wb,
    const float* __restrict__ bb1, const float* __restrict__ bb2,
    float* __restrict__ io)
{
    __shared__ ushort_t hbh[4][2][512];
    int tid = threadIdx.x, wave = tid >> 6, lane = tid & 63;
    int g = lane >> 4, q = lane & 15;
    int wgl = blockIdx.x * 4 + wave;
    int px0 = wgl * 32;
    int b   = px0 >> 16;
    int hwb = px0 & 65535;
    float* iob = io + (size_t)b * 64 * HW;

    bf16x8 bh[2][2];
#pragma unroll
    for (int pg = 0; pg < 2; ++pg) {
        int hw = hwb + pg * 16 + q;
        const float* xp = iob + hw;
        float xv[16];
#pragma unroll
        for (int j = 0; j < 8; ++j) {
            xv[j]     = xp[(g * 8 + j) * HW];
            xv[8 + j] = xp[(32 + g * 8 + j) * HW];
        }
        float s = 0.f;
#pragma unroll
        for (int j = 0; j < 16; ++j) s += xv[j];
        s += __shfl_xor(s, 16); s += __shfl_xor(s, 32);
        float mu = s * 0.015625f;
        float s2 = 0.f;
#pragma unroll
        for (int j = 0; j < 16; ++j) { float d = xv[j] - mu; s2 += d * d; }
        s2 += __shfl_xor(s2, 16); s2 += __shfl_xor(s2, 32);
        float inv = rsqrtf(s2 * 0.015625f + EPSLN);
#pragma unroll
        for (int kt = 0; kt < 2; ++kt)
#pragma unroll
            for (int j = 0; j < 8; ++j) {
                int c = kt * 32 + g * 8 + j;
                float f = (xv[kt * 8 + j] - mu) * inv * g2[c] + b2[c];
                bh[pg][kt][j] = (short)f2bf(f);
            }
    }

    const ushort_t* w1h = wb + W1_H;  const ushort_t* w1l = wb + W1_L;
    const ushort_t* w2h = wb + W2_H;  const ushort_t* w2l = wb + W2_L;

    f32x4 acc2[2][4];
#pragma unroll
    for (int pg = 0; pg < 2; ++pg)
#pragma unroll
        for (int m2 = 0; m2 < 4; ++m2)
#pragma unroll
            for (int i = 0; i < 4; ++i) acc2[pg][m2][i] = bb2[m2 * 16 + 4 * g + i];

#pragma unroll 1
    for (int mtp = 0; mtp < 8; ++mtp) {
#pragma unroll
        for (int e = 0; e < 2; ++e) {
            int mt = mtp * 2 + e;
            bf16x8 ah[2], al[2];
#pragma unroll
            for (int kt = 0; kt < 2; ++kt) {
                ah[kt] = *(const bf16x8*)(w1h + (mt * 16 + q) * 64 + kt * 32 + g * 8);
                al[kt] = *(const bf16x8*)(w1l + (mt * 16 + q) * 64 + kt * 32 + g * 8);
            }
#pragma unroll
            for (int pg = 0; pg < 2; ++pg) {
                f32x4 d;
#pragma unroll
                for (int i = 0; i < 4; ++i) d[i] = bb1[mt * 16 + 4 * g + i];
#pragma unroll
                for (int kt = 0; kt < 2; ++kt) {
                    d = __builtin_amdgcn_mfma_f32_16x16x32_bf16(ah[kt], bh[pg][kt], d, 0, 0, 0);
                    d = __builtin_amdgcn_mfma_f32_16x16x32_bf16(al[kt], bh[pg][kt], d, 0, 0, 0);
                }
                bf16x4 vh;
#pragma unroll
                for (int i = 0; i < 4; ++i)
                    vh[i] = (short)f2bf(gelu_fast(d[i]));
                int chunk = (e * 4 + g) ^ (q & 6);
                *(bf16x4*)(&hbh[wave][pg][q * 32 + chunk * 4]) = vh;
            }
        }
        // FC2: consume this 32-h slice
        bf16x8 p2h[2];
#pragma unroll
        for (int pg = 0; pg < 2; ++pg) {
            int c0 = (2 * g) ^ (q & 6);
            p2h[pg] = *(const bf16x8*)(&hbh[wave][pg][q * 32 + c0 * 4]);
        }
#pragma unroll
        for (int m2 = 0; m2 < 4; ++m2) {
            bf16x8 ah2 = *(const bf16x8*)(w2h + (m2 * 16 + q) * 256 + mtp * 32 + g * 8);
            bf16x8 al2 = *(const bf16x8*)(w2l + (m2 * 16 + q) * 256 + mtp * 32 + g * 8);
#pragma unroll
            for (int pg = 0; pg < 2; ++pg) {
                acc2[pg][m2] = __builtin_amdgcn_mfma_f32_16x16x32_bf16(ah2, p2h[pg], acc2[pg][m2], 0, 0, 0);
                acc2[pg][m2] = __builtin_amdgcn_mfma_f32_16x16x32_bf16(al2, p2h[pg], acc2[pg][m2], 0, 0, 0);
            }
        }
    }

#pragma unroll
    for (int pg = 0; pg < 2; ++pg)
#pragma unroll
        for (int m2 = 0; m2 < 4; ++m2)
#pragma unroll
            for (int i = 0; i < 4; ++i) {
                int o = m2 * 16 + 4 * g + i;
                int hw = hwb + pg * 16 + q;
                float m = gelu_fast(acc2[pg][m2][i]);
                iob[(size_t)o * HW + hw] = iob[(size_t)o * HW + hw] + m;
            }
}

// ---------------------------------------------------------------------------
extern "C" void kernel_launch(void* const* d_in, const int* in_sizes, int n_in,
                              void* d_out, int out_size, void* d_ws, size_t ws_size,
                              hipStream_t stream)
{
    const float* x     = (const float*)d_in[0];
    const float* g1    = (const float*)d_in[1];
    const float* b1    = (const float*)d_in[2];
    const float* g2    = (const float*)d_in[3];
    const float* b2    = (const float*)d_in[4];
    const float* w_qkv = (const float*)d_in[5];
    const float* b_qkv = (const float*)d_in[6];
    const float* w_out = (const float*)d_in[7];
    const float* b_out = (const float*)d_in[8];
    const float* w1    = (const float*)d_in[9];
    const float* bb1   = (const float*)d_in[10];
    const float* w2    = (const float*)d_in[11];
    const float* bb2   = (const float*)d_in[12];

    float*    out = (float*)d_out;                   // x1, then final (in place)
    ushort_t* qkv = (ushort_t*)d_ws;                 // bf16 qkv, 96 MiB
    ushort_t* wb  = (ushort_t*)d_ws + QKV_USHORTS;   // bf16 hi/lo weights

    k_prep      <<<192,  256, 0, stream>>>(w_qkv, w1, w2, w_out, wb);
    k_lnqkv_mfma<<<2048, 256, 0, stream>>>(x, g1, b1, wb, b_qkv, qkv);
    k_attn_mfma <<<1024, 256, 0, stream>>>(x, qkv, wb, b_out, out);
    k_mlp_mfma  <<<2048, 256, 0, stream>>>(g2, b2, wb, bb1, bb2, out);
}

// Round 6
// 338.933 us; speedup vs baseline: 7.1442x; 1.1531x over previous
//
#include <hip/hip_runtime.h>
#include <math.h>

#define HW    65536      // H*W
#define EPSLN 1e-5f

typedef unsigned short ushort_t;
typedef __attribute__((ext_vector_type(8))) short bf16x8;
typedef __attribute__((ext_vector_type(4))) short bf16x4;
typedef __attribute__((ext_vector_type(4))) float f32x4;

// ws layout (ushort units): [0, QKV_USHORTS) = qkv bf16 [B][12][HW][16], then weights
#define QKV_USHORTS (4*192*65536)
#define WQ_H 0
#define WQ_L 12288
#define W1_H 24576
#define W1_L 40960
#define W2_H 57344
#define W2_L 73728
#define WO_H 90112
#define WO_L 94208

__device__ __forceinline__ ushort_t f2bf(float f) {
    unsigned u = __float_as_uint(f);
    return (ushort_t)((u + 0x7FFFu + ((u >> 16) & 1u)) >> 16);   // RNE
}
__device__ __forceinline__ float bf2f(ushort_t h) {
    return __uint_as_float(((unsigned)h) << 16);
}
// tanh-based GELU: 1 exp + 1 rcp, |err| ~1e-3 abs
__device__ __forceinline__ float gelu_fast(float v) {
    float u  = v * v * v;
    float z2 = 1.5957691216057308f * v + 0.07135481627283788f * u;  // 2*0.79788456*(v+0.044715v^3)
    float e  = __expf(z2);
    float th = 1.f - 2.f * __builtin_amdgcn_rcpf(1.f + e);          // tanh(z)
    return 0.5f * v * (1.f + th);
}

// ---------------------------------------------------------------------------
// Prep: split all weights into bf16 hi/lo.
// ---------------------------------------------------------------------------
__global__ void k_prep(const float* __restrict__ wq, const float* __restrict__ w1,
                       const float* __restrict__ w2, const float* __restrict__ wo,
                       ushort_t* __restrict__ wb)
{
    int i = blockIdx.x * 256 + threadIdx.x;   // 0..49151
    float v; int oh, ol;
    if (i < 12288)      { v = wq[i];          oh = WQ_H + i;          ol = WQ_L + i; }
    else if (i < 28672) { int j = i - 12288;  v = w1[j]; oh = W1_H+j; ol = W1_L+j; }
    else if (i < 45056) { int j = i - 28672;  v = w2[j]; oh = W2_H+j; ol = W2_L+j; }
    else                { int j = i - 45056;  v = wo[j]; oh = WO_H+j; ol = WO_L+j; }
    ushort_t h = f2bf(v);
    wb[oh] = h;
    wb[ol] = f2bf(v - bf2f(h));
}

// ---------------------------------------------------------------------------
// Kernel 1: LN1 + QKV (64->192) via MFMA, 64 px/wave (4 pixel-frags per
// weight fragment). Biases/gamma/beta staged in LDS.
// qkv stored bf16 [B][12][HW][16] d-contiguous.
// ---------------------------------------------------------------------------
__global__ __launch_bounds__(256, 4) void k_lnqkv_mfma(
    const float* __restrict__ x,  const float* __restrict__ g1,
    const float* __restrict__ b1, const ushort_t* __restrict__ wb,
    const float* __restrict__ bq, ushort_t* __restrict__ qkv)
{
    __shared__ float sg1[64], sb1[64], sbq[192];
    int tid = threadIdx.x;
    if (tid < 64) { sg1[tid] = g1[tid]; sb1[tid] = b1[tid]; }
    if (tid < 192) sbq[tid] = bq[tid];
    __syncthreads();

    int wave = tid >> 6, lane = tid & 63;
    int g = lane >> 4, q = lane & 15;
    int wgl = blockIdx.x * 4 + wave;
    int px0 = wgl * 64;
    int b   = px0 >> 16;
    int hwb = px0 & 65535;
    const float* xb = x + (size_t)b * 64 * HW;

    bf16x8 bh[4][2];
#pragma unroll
    for (int pg = 0; pg < 4; ++pg) {
        int hw = hwb + pg * 16 + q;
        const float* xp = xb + hw;
        float xv[16];
#pragma unroll
        for (int j = 0; j < 8; ++j) {
            xv[j]     = xp[(g * 8 + j) * HW];
            xv[8 + j] = xp[(32 + g * 8 + j) * HW];
        }
        float s = 0.f;
#pragma unroll
        for (int j = 0; j < 16; ++j) s += xv[j];
        s += __shfl_xor(s, 16); s += __shfl_xor(s, 32);
        float mu = s * 0.015625f;
        float s2 = 0.f;
#pragma unroll
        for (int j = 0; j < 16; ++j) { float d = xv[j] - mu; s2 += d * d; }
        s2 += __shfl_xor(s2, 16); s2 += __shfl_xor(s2, 32);
        float inv = rsqrtf(s2 * 0.015625f + EPSLN);
#pragma unroll
        for (int kt = 0; kt < 2; ++kt)
#pragma unroll
            for (int j = 0; j < 8; ++j) {
                int c = kt * 32 + g * 8 + j;
                float f = (xv[kt * 8 + j] - mu) * inv * sg1[c] + sb1[c];
                bh[pg][kt][j] = (short)f2bf(f);
            }
    }

    const ushort_t* wqh = wb + WQ_H;
    const ushort_t* wql = wb + WQ_L;
    ushort_t* outb = qkv + (size_t)b * 12 * HW * 16;

#pragma unroll 2
    for (int mt = 0; mt < 12; ++mt) {
        bf16x8 ah[2], al[2];
#pragma unroll
        for (int kt = 0; kt < 2; ++kt) {
            ah[kt] = *(const bf16x8*)(wqh + (mt * 16 + q) * 64 + kt * 32 + g * 8);
            al[kt] = *(const bf16x8*)(wql + (mt * 16 + q) * 64 + kt * 32 + g * 8);
        }
        f32x4 bias = *(const f32x4*)(&sbq[mt * 16 + 4 * g]);
#pragma unroll
        for (int pg = 0; pg < 4; ++pg) {
            f32x4 d = bias;
#pragma unroll
            for (int kt = 0; kt < 2; ++kt) {
                d = __builtin_amdgcn_mfma_f32_16x16x32_bf16(ah[kt], bh[pg][kt], d, 0, 0, 0);
                d = __builtin_amdgcn_mfma_f32_16x16x32_bf16(al[kt], bh[pg][kt], d, 0, 0, 0);
            }
            bf16x4 st;
#pragma unroll
            for (int i = 0; i < 4; ++i) st[i] = (short)f2bf(d[i]);
            int hw = hwb + pg * 16 + q;
            *(bf16x4*)(outb + ((size_t)mt * HW + hw) * 16 + 4 * g) = st;
        }
    }
}

// ---------------------------------------------------------------------------
// Kernel 2: neighborhood attention, branch-free (clamped indices + 0/1 mask,
// all gathers unconditional & batchable). 4 waves/block, per-wave abuf.
// MFMA out-proj + residual.
// ---------------------------------------------------------------------------
__global__ __launch_bounds__(256) void k_attn_mfma(
    const float* __restrict__ x, const ushort_t* __restrict__ qkv,
    const ushort_t* __restrict__ wb, const float* __restrict__ bo,
    float* __restrict__ x1)
{
    __shared__ ushort_t abuf[4][64 * 64];
    __shared__ float sbo[64];
    int tid = threadIdx.x, wave = tid >> 6, lane = tid & 63;
    if (tid < 64) sbo[tid] = bo[tid];
    __syncthreads();

    int px = blockIdx.x * 256 + tid;
    int b = px >> 16, hw = px & 65535;
    int hh = hw >> 8, ww = hw & 255;
    const ushort_t* tb = qkv + (size_t)b * 12 * HW * 16;

    int   nidx[9];
    float nmask[9];
#pragma unroll
    for (int n = 0; n < 9; ++n) {
        int dy = (n / 3) * 2 - 2, dx = (n % 3) * 2 - 2;
        int y = hh + dy, xw = ww + dx;
        int yc = min(max(y, 0), 255), xc = min(max(xw, 0), 255);
        nidx[n]  = yc * 256 + xc;
        nmask[n] = (y == yc && xw == xc) ? 1.f : 0.f;
    }

#pragma unroll 1
    for (int head = 0; head < 4; ++head) {
        const ushort_t* qp = tb + ((size_t)head * HW + hw) * 16;
        bf16x8 q0 = *(const bf16x8*)qp;
        bf16x8 q1 = *(const bf16x8*)(qp + 8);
        float qv[16];
#pragma unroll
        for (int j = 0; j < 8; ++j) {
            qv[j]     = bf2f((ushort_t)q0[j]) * 0.25f;
            qv[8 + j] = bf2f((ushort_t)q1[j]) * 0.25f;
        }
        const ushort_t* kb = tb + (size_t)(4 + head) * HW * 16;
        const ushort_t* vb = tb + (size_t)(8 + head) * HW * 16;

        float sc[9];
#pragma unroll
        for (int n = 0; n < 9; ++n) {
            const ushort_t* kp = kb + (size_t)nidx[n] * 16;
            bf16x8 k0 = *(const bf16x8*)kp;
            bf16x8 k1 = *(const bf16x8*)(kp + 8);
            float s = 0.f;
#pragma unroll
            for (int j = 0; j < 8; ++j) {
                s += qv[j]     * bf2f((ushort_t)k0[j]);
                s += qv[8 + j] * bf2f((ushort_t)k1[j]);
            }
            sc[n] = s * nmask[n];
        }
        float mx = sc[0];
#pragma unroll
        for (int n = 1; n < 9; ++n) mx = fmaxf(mx, sc[n]);

        float ew[9], sum = 0.f;
#pragma unroll
        for (int n = 0; n < 9; ++n) {
            float e = __expf(sc[n] - mx);
            sum += e;
            ew[n] = e * nmask[n];
        }

        float o16[16];
#pragma unroll
        for (int d = 0; d < 16; ++d) o16[d] = 0.f;
#pragma unroll
        for (int n = 0; n < 9; ++n) {
            const ushort_t* vp = vb + (size_t)nidx[n] * 16;
            bf16x8 v0 = *(const bf16x8*)vp;
            bf16x8 v1 = *(const bf16x8*)(vp + 8);
            float a = ew[n];
#pragma unroll
            for (int j = 0; j < 8; ++j) {
                o16[j]     += a * bf2f((ushort_t)v0[j]);
                o16[8 + j] += a * bf2f((ushort_t)v1[j]);
            }
        }
        float isum = __builtin_amdgcn_rcpf(sum);

        bf16x8 w0, w1v;
#pragma unroll
        for (int j = 0; j < 8; ++j) {
            w0[j]  = (short)f2bf(o16[j] * isum);
            w1v[j] = (short)f2bf(o16[8 + j] * isum);
        }
        int c0 = (head * 2)     ^ (lane & 7);
        int c1 = (head * 2 + 1) ^ (lane & 7);
        *(bf16x8*)(&abuf[wave][lane * 64 + c0 * 8]) = w0;
        *(bf16x8*)(&abuf[wave][lane * 64 + c1 * 8]) = w1v;
    }
    __syncthreads();

    int g = lane >> 4, q = lane & 15;
    const ushort_t* woh = wb + WO_H;
    const ushort_t* wol = wb + WO_L;
    int hwwb = (blockIdx.x * 256 + wave * 64) & 65535;

#pragma unroll 1
    for (int pg = 0; pg < 4; ++pg) {
        int r = pg * 16 + q;
        bf16x8 bb[2];
#pragma unroll
        for (int kt = 0; kt < 2; ++kt) {
            int c = (kt * 4 + g) ^ (r & 7);
            bb[kt] = *(const bf16x8*)(&abuf[wave][r * 64 + c * 8]);
        }
        int hwg = hwwb + pg * 16 + q;
#pragma unroll
        for (int mt = 0; mt < 4; ++mt) {
            f32x4 d = *(const f32x4*)(&sbo[mt * 16 + 4 * g]);
#pragma unroll
            for (int kt = 0; kt < 2; ++kt) {
                bf16x8 ah = *(const bf16x8*)(woh + (mt * 16 + q) * 64 + kt * 32 + g * 8);
                bf16x8 al = *(const bf16x8*)(wol + (mt * 16 + q) * 64 + kt * 32 + g * 8);
                d = __builtin_amdgcn_mfma_f32_16x16x32_bf16(ah, bb[kt], d, 0, 0, 0);
                d = __builtin_amdgcn_mfma_f32_16x16x32_bf16(al, bb[kt], d, 0, 0, 0);
            }
#pragma unroll
            for (int i = 0; i < 4; ++i) {
                int o = mt * 16 + 4 * g + i;
                size_t idx = (size_t)(b * 64 + o) * HW + hwg;
                x1[idx] = x[idx] + d[i];
            }
        }
    }
}

// ---------------------------------------------------------------------------
// Kernel 3: fused MLP via MFMA, 64 px/wave, biases in LDS, double-buffered
// h-retile LDS, tanh-GELU.
// ---------------------------------------------------------------------------
__global__ __launch_bounds__(256, 3) void k_mlp_mfma(
    const float* __restrict__ g2, const float* __restrict__ b2,
    const ushort_t* __restrict__ wb,
    const float* __restrict__ bb1, const float* __restrict__ bb2,
    float* __restrict__ io)
{
    __shared__ ushort_t hbh[4][2][2048];   // [wave][buf][pg*512 + ...]
    __shared__ float sg2[64], sb2[64], sbb1[256], sbb2[64];
    int tid = threadIdx.x;
    sbb1[tid] = bb1[tid];
    if (tid < 64) { sg2[tid] = g2[tid]; sb2[tid] = b2[tid]; sbb2[tid] = bb2[tid]; }
    __syncthreads();

    int wave = tid >> 6, lane = tid & 63;
    int g = lane >> 4, q = lane & 15;
    int wgl = blockIdx.x * 4 + wave;
    int px0 = wgl * 64;
    int b   = px0 >> 16;
    int hwb = px0 & 65535;
    float* iob = io + (size_t)b * 64 * HW;

    bf16x8 bh[4][2];
#pragma unroll
    for (int pg = 0; pg < 4; ++pg) {
        int hw = hwb + pg * 16 + q;
        const float* xp = iob + hw;
        float xv[16];
#pragma unroll
        for (int j = 0; j < 8; ++j) {
            xv[j]     = xp[(g * 8 + j) * HW];
            xv[8 + j] = xp[(32 + g * 8 + j) * HW];
        }
        float s = 0.f;
#pragma unroll
        for (int j = 0; j < 16; ++j) s += xv[j];
        s += __shfl_xor(s, 16); s += __shfl_xor(s, 32);
        float mu = s * 0.015625f;
        float s2 = 0.f;
#pragma unroll
        for (int j = 0; j < 16; ++j) { float d = xv[j] - mu; s2 += d * d; }
        s2 += __shfl_xor(s2, 16); s2 += __shfl_xor(s2, 32);
        float inv = rsqrtf(s2 * 0.015625f + EPSLN);
#pragma unroll
        for (int kt = 0; kt < 2; ++kt)
#pragma unroll
            for (int j = 0; j < 8; ++j) {
                int c = kt * 32 + g * 8 + j;
                float f = (xv[kt * 8 + j] - mu) * inv * sg2[c] + sb2[c];
                bh[pg][kt][j] = (short)f2bf(f);
            }
    }

    const ushort_t* w1h = wb + W1_H;  const ushort_t* w1l = wb + W1_L;
    const ushort_t* w2h = wb + W2_H;  const ushort_t* w2l = wb + W2_L;

    f32x4 acc2[4][4];   // [pg][m2]
#pragma unroll
    for (int m2 = 0; m2 < 4; ++m2) {
        f32x4 binit = *(const f32x4*)(&sbb2[m2 * 16 + 4 * g]);
#pragma unroll
        for (int pg = 0; pg < 4; ++pg) acc2[pg][m2] = binit;
    }

#pragma unroll 1
    for (int mtp = 0; mtp < 8; ++mtp) {
        int buf = mtp & 1;
#pragma unroll
        for (int e = 0; e < 2; ++e) {
            int mt = mtp * 2 + e;
            bf16x8 ah[2], al[2];
#pragma unroll
            for (int kt = 0; kt < 2; ++kt) {
                ah[kt] = *(const bf16x8*)(w1h + (mt * 16 + q) * 64 + kt * 32 + g * 8);
                al[kt] = *(const bf16x8*)(w1l + (mt * 16 + q) * 64 + kt * 32 + g * 8);
            }
            f32x4 b1v = *(const f32x4*)(&sbb1[mt * 16 + 4 * g]);
            int chunk = (e * 4 + g) ^ (q & 6);
#pragma unroll
            for (int pg = 0; pg < 4; ++pg) {
                f32x4 d = b1v;
#pragma unroll
                for (int kt = 0; kt < 2; ++kt) {
                    d = __builtin_amdgcn_mfma_f32_16x16x32_bf16(ah[kt], bh[pg][kt], d, 0, 0, 0);
                    d = __builtin_amdgcn_mfma_f32_16x16x32_bf16(al[kt], bh[pg][kt], d, 0, 0, 0);
                }
                bf16x4 vh;
#pragma unroll
                for (int i = 0; i < 4; ++i)
                    vh[i] = (short)f2bf(gelu_fast(d[i]));
                *(bf16x4*)(&hbh[wave][buf][pg * 512 + q * 32 + chunk * 4]) = vh;
            }
        }
        // FC2: consume this 32-h slice
        int c0 = (2 * g) ^ (q & 6);
        bf16x8 p2[4];
#pragma unroll
        for (int pg = 0; pg < 4; ++pg)
            p2[pg] = *(const bf16x8*)(&hbh[wave][buf][pg * 512 + q * 32 + c0 * 4]);
#pragma unroll
        for (int m2 = 0; m2 < 4; ++m2) {
            bf16x8 ah2 = *(const bf16x8*)(w2h + (m2 * 16 + q) * 256 + mtp * 32 + g * 8);
            bf16x8 al2 = *(const bf16x8*)(w2l + (m2 * 16 + q) * 256 + mtp * 32 + g * 8);
#pragma unroll
            for (int pg = 0; pg < 4; ++pg) {
                acc2[pg][m2] = __builtin_amdgcn_mfma_f32_16x16x32_bf16(ah2, p2[pg], acc2[pg][m2], 0, 0, 0);
                acc2[pg][m2] = __builtin_amdgcn_mfma_f32_16x16x32_bf16(al2, p2[pg], acc2[pg][m2], 0, 0, 0);
            }
        }
    }

#pragma unroll
    for (int pg = 0; pg < 4; ++pg)
#pragma unroll
        for (int m2 = 0; m2 < 4; ++m2)
#pragma unroll
            for (int i = 0; i < 4; ++i) {
                int o = m2 * 16 + 4 * g + i;
                int hw = hwb + pg * 16 + q;
                float m = gelu_fast(acc2[pg][m2][i]);
                iob[(size_t)o * HW + hw] = iob[(size_t)o * HW + hw] + m;
            }
}

// ---------------------------------------------------------------------------
extern "C" void kernel_launch(void* const* d_in, const int* in_sizes, int n_in,
                              void* d_out, int out_size, void* d_ws, size_t ws_size,
                              hipStream_t stream)
{
    const float* x     = (const float*)d_in[0];
    const float* g1    = (const float*)d_in[1];
    const float* b1    = (const float*)d_in[2];
    const float* g2    = (const float*)d_in[3];
    const float* b2    = (const float*)d_in[4];
    const float* w_qkv = (const float*)d_in[5];
    const float* b_qkv = (const float*)d_in[6];
    const float* w_out = (const float*)d_in[7];
    const float* b_out = (const float*)d_in[8];
    const float* w1    = (const float*)d_in[9];
    const float* bb1   = (const float*)d_in[10];
    const float* w2    = (const float*)d_in[11];
    const float* bb2   = (const float*)d_in[12];

    float*    out = (float*)d_out;                   // x1, then final (in place)
    ushort_t* qkv = (ushort_t*)d_ws;                 // bf16 qkv, 96 MiB
    ushort_t* wb  = (ushort_t*)d_ws + QKV_USHORTS;   // bf16 hi/lo weights

    k_prep      <<<192,  256, 0, stream>>>(w_qkv, w1, w2, w_out, wb);
    k_lnqkv_mfma<<<1024, 256, 0, stream>>>(x, g1, b1, wb, b_qkv, qkv);
    k_attn_mfma <<<1024, 256, 0, stream>>>(x, qkv, wb, b_out, out);
    k_mlp_mfma  <<<1024, 256, 0, stream>>>(g2, b2, wb, bb1, bb2, out);
}

// Round 7
// 292.275 us; speedup vs baseline: 8.2847x; 1.1596x over previous
//
#include <hip/hip_runtime.h>
#include <math.h>

#define HW    65536      // H*W
#define EPSLN 1e-5f

typedef unsigned short ushort_t;
typedef __attribute__((ext_vector_type(8))) short bf16x8;
typedef __attribute__((ext_vector_type(4))) short bf16x4;
typedef __attribute__((ext_vector_type(4))) float f32x4;

// ws layout (ushort units): [0, QKV_USHORTS) = qkv bf16 [B][12][HW][16], then weights
#define QKV_USHORTS (4*192*65536)
#define WQ_H 0
#define WQ_L 12288
#define W1_H 24576
#define W1_L 40960
#define W2_H 57344
#define W2_L 73728
#define WO_H 90112
#define WO_L 94208

__device__ __forceinline__ ushort_t f2bf(float f) {
    unsigned u = __float_as_uint(f);
    return (ushort_t)((u + 0x7FFFu + ((u >> 16) & 1u)) >> 16);   // RNE
}
__device__ __forceinline__ float bf2f(ushort_t h) {
    return __uint_as_float(((unsigned)h) << 16);
}
// tanh-based GELU: 1 exp + 1 rcp, |err| ~1e-3 abs
__device__ __forceinline__ float gelu_fast(float v) {
    float u  = v * v * v;
    float z2 = 1.5957691216057308f * v + 0.07135481627283788f * u;
    float e  = __expf(z2);
    float th = 1.f - 2.f * __builtin_amdgcn_rcpf(1.f + e);
    return 0.5f * v * (1.f + th);
}

// ---------------------------------------------------------------------------
// Prep: split all weights into bf16 hi/lo.
// ---------------------------------------------------------------------------
__global__ void k_prep(const float* __restrict__ wq, const float* __restrict__ w1,
                       const float* __restrict__ w2, const float* __restrict__ wo,
                       ushort_t* __restrict__ wb)
{
    int i = blockIdx.x * 256 + threadIdx.x;   // 0..49151
    float v; int oh, ol;
    if (i < 12288)      { v = wq[i];          oh = WQ_H + i;          ol = WQ_L + i; }
    else if (i < 28672) { int j = i - 12288;  v = w1[j]; oh = W1_H+j; ol = W1_L+j; }
    else if (i < 45056) { int j = i - 28672;  v = w2[j]; oh = W2_H+j; ol = W2_L+j; }
    else                { int j = i - 45056;  v = wo[j]; oh = WO_H+j; ol = WO_L+j; }
    ushort_t h = f2bf(v);
    wb[oh] = h;
    wb[ol] = f2bf(v - bf2f(h));
}

// ---------------------------------------------------------------------------
// Kernel 1: LN1 + QKV (64->192) via MFMA. 1 wave/block, 64 px/wave.
// qkv stored bf16 [B][12][HW][16] d-contiguous.
// ---------------------------------------------------------------------------
__global__ __launch_bounds__(64, 5) void k_lnqkv_mfma(
    const float* __restrict__ x,  const float* __restrict__ g1,
    const float* __restrict__ b1, const ushort_t* __restrict__ wb,
    const float* __restrict__ bq, ushort_t* __restrict__ qkv)
{
    __shared__ float sg1[64], sb1[64], sbq[192];
    int tid = threadIdx.x;
    sg1[tid] = g1[tid]; sb1[tid] = b1[tid];
#pragma unroll
    for (int i = tid; i < 192; i += 64) sbq[i] = bq[i];
    __syncthreads();

    int lane = tid;
    int g = lane >> 4, q = lane & 15;
    int px0 = blockIdx.x * 64;
    int b   = px0 >> 16;
    int hwb = px0 & 65535;
    const float* xb = x + (size_t)b * 64 * HW;

    bf16x8 bh[4][2];
#pragma unroll
    for (int pg = 0; pg < 4; ++pg) {
        int hw = hwb + pg * 16 + q;
        const float* xp = xb + hw;
        float xv[16];
#pragma unroll
        for (int j = 0; j < 8; ++j) {
            xv[j]     = xp[(g * 8 + j) * HW];
            xv[8 + j] = xp[(32 + g * 8 + j) * HW];
        }
        float s = 0.f;
#pragma unroll
        for (int j = 0; j < 16; ++j) s += xv[j];
        s += __shfl_xor(s, 16); s += __shfl_xor(s, 32);
        float mu = s * 0.015625f;
        float s2 = 0.f;
#pragma unroll
        for (int j = 0; j < 16; ++j) { float d = xv[j] - mu; s2 += d * d; }
        s2 += __shfl_xor(s2, 16); s2 += __shfl_xor(s2, 32);
        float inv = rsqrtf(s2 * 0.015625f + EPSLN);
#pragma unroll
        for (int kt = 0; kt < 2; ++kt)
#pragma unroll
            for (int j = 0; j < 8; ++j) {
                int c = kt * 32 + g * 8 + j;
                float f = (xv[kt * 8 + j] - mu) * inv * sg1[c] + sb1[c];
                bh[pg][kt][j] = (short)f2bf(f);
            }
    }

    const ushort_t* wqh = wb + WQ_H;
    const ushort_t* wql = wb + WQ_L;
    ushort_t* outb = qkv + (size_t)b * 12 * HW * 16;

#pragma unroll 2
    for (int mt = 0; mt < 12; ++mt) {
        bf16x8 ah[2], al[2];
#pragma unroll
        for (int kt = 0; kt < 2; ++kt) {
            ah[kt] = *(const bf16x8*)(wqh + (mt * 16 + q) * 64 + kt * 32 + g * 8);
            al[kt] = *(const bf16x8*)(wql + (mt * 16 + q) * 64 + kt * 32 + g * 8);
        }
        f32x4 bias = *(const f32x4*)(&sbq[mt * 16 + 4 * g]);
#pragma unroll
        for (int pg = 0; pg < 4; ++pg) {
            f32x4 d = bias;
#pragma unroll
            for (int kt = 0; kt < 2; ++kt) {
                d = __builtin_amdgcn_mfma_f32_16x16x32_bf16(ah[kt], bh[pg][kt], d, 0, 0, 0);
                d = __builtin_amdgcn_mfma_f32_16x16x32_bf16(al[kt], bh[pg][kt], d, 0, 0, 0);
            }
            bf16x4 st;
#pragma unroll
            for (int i = 0; i < 4; ++i) st[i] = (short)f2bf(d[i]);
            int hw = hwb + pg * 16 + q;
            *(bf16x4*)(outb + ((size_t)mt * HW + hw) * 16 + 4 * g) = st;
        }
    }
}

// ---------------------------------------------------------------------------
// Kernel 2: neighborhood attention, branch-free gathers, 1 wave/block
// (64 px), per-block abuf (8 KB). MFMA out-proj (mt-outer) + residual.
// ---------------------------------------------------------------------------
__global__ __launch_bounds__(64, 4) void k_attn_mfma(
    const float* __restrict__ x, const ushort_t* __restrict__ qkv,
    const ushort_t* __restrict__ wb, const float* __restrict__ bo,
    float* __restrict__ x1)
{
    __shared__ ushort_t abuf[64 * 64];
    __shared__ float sbo[64];
    int lane = threadIdx.x;
    sbo[lane] = bo[lane];
    __syncthreads();

    int px = blockIdx.x * 64 + lane;
    int b = px >> 16, hw = px & 65535;
    int hh = hw >> 8, ww = hw & 255;
    const ushort_t* tb = qkv + (size_t)b * 12 * HW * 16;

    int   nidx[9];
    float nmask[9];
#pragma unroll
    for (int n = 0; n < 9; ++n) {
        int dy = (n / 3) * 2 - 2, dx = (n % 3) * 2 - 2;
        int y = hh + dy, xw = ww + dx;
        int yc = min(max(y, 0), 255), xc = min(max(xw, 0), 255);
        nidx[n]  = yc * 256 + xc;
        nmask[n] = (y == yc && xw == xc) ? 1.f : 0.f;
    }

#pragma unroll 1
    for (int head = 0; head < 4; ++head) {
        const ushort_t* qp = tb + ((size_t)head * HW + hw) * 16;
        bf16x8 q0 = *(const bf16x8*)qp;
        bf16x8 q1 = *(const bf16x8*)(qp + 8);
        float qv[16];
#pragma unroll
        for (int j = 0; j < 8; ++j) {
            qv[j]     = bf2f((ushort_t)q0[j]) * 0.25f;
            qv[8 + j] = bf2f((ushort_t)q1[j]) * 0.25f;
        }
        const ushort_t* kb = tb + (size_t)(4 + head) * HW * 16;
        const ushort_t* vb = tb + (size_t)(8 + head) * HW * 16;

        float sc[9];
#pragma unroll
        for (int n = 0; n < 9; ++n) {
            const ushort_t* kp = kb + (size_t)nidx[n] * 16;
            bf16x8 k0 = *(const bf16x8*)kp;
            bf16x8 k1 = *(const bf16x8*)(kp + 8);
            float s = 0.f;
#pragma unroll
            for (int j = 0; j < 8; ++j) {
                s += qv[j]     * bf2f((ushort_t)k0[j]);
                s += qv[8 + j] * bf2f((ushort_t)k1[j]);
            }
            sc[n] = s * nmask[n];
        }
        float mx = sc[0];
#pragma unroll
        for (int n = 1; n < 9; ++n) mx = fmaxf(mx, sc[n]);

        float ew[9], sum = 0.f;
#pragma unroll
        for (int n = 0; n < 9; ++n) {
            float e = __expf(sc[n] - mx);
            sum += e;
            ew[n] = e * nmask[n];
        }

        float o16[16];
#pragma unroll
        for (int d = 0; d < 16; ++d) o16[d] = 0.f;
#pragma unroll
        for (int n = 0; n < 9; ++n) {
            const ushort_t* vp = vb + (size_t)nidx[n] * 16;
            bf16x8 v0 = *(const bf16x8*)vp;
            bf16x8 v1 = *(const bf16x8*)(vp + 8);
            float a = ew[n];
#pragma unroll
            for (int j = 0; j < 8; ++j) {
                o16[j]     += a * bf2f((ushort_t)v0[j]);
                o16[8 + j] += a * bf2f((ushort_t)v1[j]);
            }
        }
        float isum = __builtin_amdgcn_rcpf(sum);

        bf16x8 w0, w1v;
#pragma unroll
        for (int j = 0; j < 8; ++j) {
            w0[j]  = (short)f2bf(o16[j] * isum);
            w1v[j] = (short)f2bf(o16[8 + j] * isum);
        }
        int c0 = (head * 2)     ^ (lane & 7);
        int c1 = (head * 2 + 1) ^ (lane & 7);
        *(bf16x8*)(&abuf[lane * 64 + c0 * 8]) = w0;
        *(bf16x8*)(&abuf[lane * 64 + c1 * 8]) = w1v;
    }
    __syncthreads();

    int g = lane >> 4, q = lane & 15;
    const ushort_t* woh = wb + WO_H;
    const ushort_t* wol = wb + WO_L;
    int hwwb = (blockIdx.x * 64) & 65535;
    const float* xb = x + (size_t)b * 64 * HW;
    float* x1b = x1 + (size_t)b * 64 * HW;

    // Pre-read all attnout fragments (mt-outer loop => weights loaded once).
    bf16x8 bb[4][2];
#pragma unroll
    for (int pg = 0; pg < 4; ++pg) {
        int r = pg * 16 + q;
#pragma unroll
        for (int kt = 0; kt < 2; ++kt) {
            int c = (kt * 4 + g) ^ (r & 7);
            bb[pg][kt] = *(const bf16x8*)(&abuf[r * 64 + c * 8]);
        }
    }

#pragma unroll 1
    for (int mt = 0; mt < 4; ++mt) {
        bf16x8 ah[2], al[2];
#pragma unroll
        for (int kt = 0; kt < 2; ++kt) {
            ah[kt] = *(const bf16x8*)(woh + (mt * 16 + q) * 64 + kt * 32 + g * 8);
            al[kt] = *(const bf16x8*)(wol + (mt * 16 + q) * 64 + kt * 32 + g * 8);
        }
        f32x4 bias = *(const f32x4*)(&sbo[mt * 16 + 4 * g]);
#pragma unroll
        for (int pg = 0; pg < 4; ++pg) {
            f32x4 d = bias;
#pragma unroll
            for (int kt = 0; kt < 2; ++kt) {
                d = __builtin_amdgcn_mfma_f32_16x16x32_bf16(ah[kt], bb[pg][kt], d, 0, 0, 0);
                d = __builtin_amdgcn_mfma_f32_16x16x32_bf16(al[kt], bb[pg][kt], d, 0, 0, 0);
            }
            int hwg = hwwb + pg * 16 + q;
#pragma unroll
            for (int i = 0; i < 4; ++i) {
                int o = mt * 16 + 4 * g + i;
                x1b[(size_t)o * HW + hwg] = xb[(size_t)o * HW + hwg] + d[i];
            }
        }
    }
}

// ---------------------------------------------------------------------------
// Kernel 3: fused MLP via MFMA, 1 wave/block, 64 px/wave, double-buffered
// h-retile (8 KB), tanh-GELU.
// ---------------------------------------------------------------------------
__global__ __launch_bounds__(64, 6) void k_mlp_mfma(
    const float* __restrict__ g2, const float* __restrict__ b2,
    const ushort_t* __restrict__ wb,
    const float* __restrict__ bb1, const float* __restrict__ bb2,
    float* __restrict__ io)
{
    __shared__ ushort_t hbh[2][2048];   // [buf][pg*512 + ...]
    __shared__ float sg2[64], sb2[64], sbb1[256], sbb2[64];
    int tid = threadIdx.x;
    sg2[tid] = g2[tid]; sb2[tid] = b2[tid]; sbb2[tid] = bb2[tid];
#pragma unroll
    for (int i = tid; i < 256; i += 64) sbb1[i] = bb1[i];
    __syncthreads();

    int lane = tid;
    int g = lane >> 4, q = lane & 15;
    int px0 = blockIdx.x * 64;
    int b   = px0 >> 16;
    int hwb = px0 & 65535;
    float* iob = io + (size_t)b * 64 * HW;

    bf16x8 bh[4][2];
#pragma unroll
    for (int pg = 0; pg < 4; ++pg) {
        int hw = hwb + pg * 16 + q;
        const float* xp = iob + hw;
        float xv[16];
#pragma unroll
        for (int j = 0; j < 8; ++j) {
            xv[j]     = xp[(g * 8 + j) * HW];
            xv[8 + j] = xp[(32 + g * 8 + j) * HW];
        }
        float s = 0.f;
#pragma unroll
        for (int j = 0; j < 16; ++j) s += xv[j];
        s += __shfl_xor(s, 16); s += __shfl_xor(s, 32);
        float mu = s * 0.015625f;
        float s2 = 0.f;
#pragma unroll
        for (int j = 0; j < 16; ++j) { float d = xv[j] - mu; s2 += d * d; }
        s2 += __shfl_xor(s2, 16); s2 += __shfl_xor(s2, 32);
        float inv = rsqrtf(s2 * 0.015625f + EPSLN);
#pragma unroll
        for (int kt = 0; kt < 2; ++kt)
#pragma unroll
            for (int j = 0; j < 8; ++j) {
                int c = kt * 32 + g * 8 + j;
                float f = (xv[kt * 8 + j] - mu) * inv * sg2[c] + sb2[c];
                bh[pg][kt][j] = (short)f2bf(f);
            }
    }

    const ushort_t* w1h = wb + W1_H;  const ushort_t* w1l = wb + W1_L;
    const ushort_t* w2h = wb + W2_H;  const ushort_t* w2l = wb + W2_L;

    f32x4 acc2[4][4];   // [pg][m2]
#pragma unroll
    for (int m2 = 0; m2 < 4; ++m2) {
        f32x4 binit = *(const f32x4*)(&sbb2[m2 * 16 + 4 * g]);
#pragma unroll
        for (int pg = 0; pg < 4; ++pg) acc2[pg][m2] = binit;
    }

#pragma unroll 1
    for (int mtp = 0; mtp < 8; ++mtp) {
        int buf = mtp & 1;
#pragma unroll
        for (int e = 0; e < 2; ++e) {
            int mt = mtp * 2 + e;
            bf16x8 ah[2], al[2];
#pragma unroll
            for (int kt = 0; kt < 2; ++kt) {
                ah[kt] = *(const bf16x8*)(w1h + (mt * 16 + q) * 64 + kt * 32 + g * 8);
                al[kt] = *(const bf16x8*)(w1l + (mt * 16 + q) * 64 + kt * 32 + g * 8);
            }
            f32x4 b1v = *(const f32x4*)(&sbb1[mt * 16 + 4 * g]);
            int chunk = (e * 4 + g) ^ (q & 6);
#pragma unroll
            for (int pg = 0; pg < 4; ++pg) {
                f32x4 d = b1v;
#pragma unroll
                for (int kt = 0; kt < 2; ++kt) {
                    d = __builtin_amdgcn_mfma_f32_16x16x32_bf16(ah[kt], bh[pg][kt], d, 0, 0, 0);
                    d = __builtin_amdgcn_mfma_f32_16x16x32_bf16(al[kt], bh[pg][kt], d, 0, 0, 0);
                }
                bf16x4 vh;
#pragma unroll
                for (int i = 0; i < 4; ++i)
                    vh[i] = (short)f2bf(gelu_fast(d[i]));
                *(bf16x4*)(&hbh[buf][pg * 512 + q * 32 + chunk * 4]) = vh;
            }
        }
        // FC2: consume this 32-h slice
        int c0 = (2 * g) ^ (q & 6);
        bf16x8 p2[4];
#pragma unroll
        for (int pg = 0; pg < 4; ++pg)
            p2[pg] = *(const bf16x8*)(&hbh[buf][pg * 512 + q * 32 + c0 * 4]);
#pragma unroll
        for (int m2 = 0; m2 < 4; ++m2) {
            bf16x8 ah2 = *(const bf16x8*)(w2h + (m2 * 16 + q) * 256 + mtp * 32 + g * 8);
            bf16x8 al2 = *(const bf16x8*)(w2l + (m2 * 16 + q) * 256 + mtp * 32 + g * 8);
#pragma unroll
            for (int pg = 0; pg < 4; ++pg) {
                acc2[pg][m2] = __builtin_amdgcn_mfma_f32_16x16x32_bf16(ah2, p2[pg], acc2[pg][m2], 0, 0, 0);
                acc2[pg][m2] = __builtin_amdgcn_mfma_f32_16x16x32_bf16(al2, p2[pg], acc2[pg][m2], 0, 0, 0);
            }
        }
    }

#pragma unroll
    for (int pg = 0; pg < 4; ++pg)
#pragma unroll
        for (int m2 = 0; m2 < 4; ++m2)
#pragma unroll
            for (int i = 0; i < 4; ++i) {
                int o = m2 * 16 + 4 * g + i;
                int hw = hwb + pg * 16 + q;
                float m = gelu_fast(acc2[pg][m2][i]);
                iob[(size_t)o * HW + hw] = iob[(size_t)o * HW + hw] + m;
            }
}

// ---------------------------------------------------------------------------
extern "C" void kernel_launch(void* const* d_in, const int* in_sizes, int n_in,
                              void* d_out, int out_size, void* d_ws, size_t ws_size,
                              hipStream_t stream)
{
    const float* x     = (const float*)d_in[0];
    const float* g1    = (const float*)d_in[1];
    const float* b1    = (const float*)d_in[2];
    const float* g2    = (const float*)d_in[3];
    const float* b2    = (const float*)d_in[4];
    const float* w_qkv = (const float*)d_in[5];
    const float* b_qkv = (const float*)d_in[6];
    const float* w_out = (const float*)d_in[7];
    const float* b_out = (const float*)d_in[8];
    const float* w1    = (const float*)d_in[9];
    const float* bb1   = (const float*)d_in[10];
    const float* w2    = (const float*)d_in[11];
    const float* bb2   = (const float*)d_in[12];

    float*    out = (float*)d_out;                   // x1, then final (in place)
    ushort_t* qkv = (ushort_t*)d_ws;                 // bf16 qkv, 96 MiB
    ushort_t* wb  = (ushort_t*)d_ws + QKV_USHORTS;   // bf16 hi/lo weights

    k_prep      <<<192,  256, 0, stream>>>(w_qkv, w1, w2, w_out, wb);
    k_lnqkv_mfma<<<4096, 64, 0, stream>>>(x, g1, b1, wb, b_qkv, qkv);
    k_attn_mfma <<<4096, 64, 0, stream>>>(x, qkv, wb, b_out, out);
    k_mlp_mfma  <<<4096, 64, 0, stream>>>(g2, b2, wb, bb1, bb2, out);
}